// Round 2
// baseline (693.849 us; speedup 1.0000x reference)
//
#include <hip/hip_runtime.h>

typedef __attribute__((ext_vector_type(8))) __bf16 bf16x8;
typedef __attribute__((ext_vector_type(2))) __bf16 bf16x2;
typedef __attribute__((ext_vector_type(4))) float f32x4;

#define MFMA16(a,b,c) __builtin_amdgcn_mfma_f32_16x16x32_bf16(a,b,c,0,0,0)

static constexpr int HW = 65536;   // 256*256
static constexpr int WD = 256;
static constexpr int NB = 2;       // batch
static constexpr float INV_N = 1.0f / 1048576.0f;  // 8ch*65536px*2cosets
static constexpr float EPSV = 1e-5f;

// workspace layout (bytes)
static constexpr size_t OFF_STATS = 0;                 // 96 floats
static constexpr size_t OFF_A1 = 1024;                 // 20480 bf16
static constexpr size_t OFF_A2 = OFF_A1 + 40960;
static constexpr size_t OFF_XT = OFF_A2 + 40960;       // 82944
static constexpr size_t SZ_T   = (size_t)2 * NB * HW * 64 * 2;  // 32 MiB
static constexpr size_t OFF_S  = OFF_XT + SZ_T;
static constexpr size_t OFF_H  = OFF_S + SZ_T;

// ---------------- weight prep: A[o][k], k: [0,64)=center, [64+t*64+c]=tap t ----------------
__global__ void k_prep(const float* __restrict__ wc1, const float* __restrict__ wk1,
                       const float* __restrict__ wc2, const float* __restrict__ wk2,
                       __bf16* __restrict__ A1, __bf16* __restrict__ A2) {
  const int stage = blockIdx.x;
  const float* wc = stage ? wc2 : wc1;
  const float* wk = stage ? wk2 : wk1;
  __bf16* A = stage ? A2 : A1;
  for (int idx = threadIdx.x; idx < 64 * 320; idx += blockDim.x) {
    int o = idx / 320, k = idx - o * 320;
    float v;
    if (k < 64) v = wc[o * 64 + k];
    else {
      int t = (k - 64) >> 6;
      int c = k & 63;
      v = wk[(o * 64 + c) * 4 + t];
    }
    A[idx] = (__bf16)v;
  }
}

// ---------------- k1: stats1 (exact fp32) + skip GEMM + NHWC bf16 transpose ----------------
__global__ __launch_bounds__(256) void k1(
    const float* __restrict__ x0, const float* __restrict__ x1,
    const float* __restrict__ wskip, const float* __restrict__ bskip,
    __bf16* __restrict__ xt, __bf16* __restrict__ sout, float* __restrict__ st) {
  const int row = blockIdx.x;   // 0..255 (H row)
  const int b   = blockIdx.y;
  const int co  = blockIdx.z;
  const float* x = co ? x1 : x0;
  __shared__ __attribute__((aligned(16))) __bf16 tile[256 * 72];
  const int t = threadIdx.x;    // = pixel x within row

  const float* xbase = x + (size_t)b * 64 * HW + (size_t)row * WD + t;
  __bf16* xtbase = xt + (((size_t)(co * NB + b) * HW) + (size_t)row * WD + t) * 64;

  for (int cg = 0; cg < 8; ++cg) {
    bf16x8 v;
    float sum = 0.f, sq = 0.f;
#pragma unroll
    for (int j = 0; j < 8; ++j) {
      float f = xbase[(size_t)(cg * 8 + j) * HW];
      v[j] = (__bf16)f;
      sum += f;
      sq = fmaf(f, f, sq);
    }
    *(bf16x8*)&tile[t * 72 + cg * 8] = v;
    *(bf16x8*)&xtbase[cg * 8] = v;
#pragma unroll
    for (int m = 1; m < 64; m <<= 1) {
      sum += __shfl_xor(sum, m, 64);
      sq  += __shfl_xor(sq, m, 64);
    }
    if ((t & 63) == 0) {
      atomicAdd(&st[b * 8 + cg], sum);
      atomicAdd(&st[16 + b * 8 + cg], sq);
    }
  }
  __syncthreads();

  const int wv = t >> 6, lane = t & 63, ln = lane & 15, q = lane >> 4;
  const int ch0 = wv * 16 + q * 4;
  bf16x8 a0, a1;
#pragma unroll
  for (int j = 0; j < 8; ++j) {
    a0[j] = (__bf16)wskip[(wv * 16 + ln) * 64 + q * 8 + j];
    a1[j] = (__bf16)wskip[(wv * 16 + ln) * 64 + 32 + q * 8 + j];
  }
  float bia[4];
#pragma unroll
  for (int r = 0; r < 4; ++r) bia[r] = bskip[ch0 + r];

  float ssum = 0.f, ssq = 0.f;
  for (int n = 0; n < 16; ++n) {
    f32x4 acc = {0.f, 0.f, 0.f, 0.f};
    bf16x8 b0 = *(const bf16x8*)&tile[(n * 16 + ln) * 72 + q * 8];
    bf16x8 b1 = *(const bf16x8*)&tile[(n * 16 + ln) * 72 + 32 + q * 8];
    acc = MFMA16(a0, b0, acc);
    acc = MFMA16(a1, b1, acc);
    float v[4];
#pragma unroll
    for (int r = 0; r < 4; ++r) {
      v[r] = acc[r] + bia[r];
      ssum += v[r];
      ssq = fmaf(v[r], v[r], ssq);
    }
    size_t sb = (((size_t)(co * NB + b) * HW) + (size_t)row * WD + n * 16 + ln) * 64 + ch0;
    bf16x2 p0; p0[0] = (__bf16)v[0]; p0[1] = (__bf16)v[1];
    bf16x2 p1; p1[0] = (__bf16)v[2]; p1[1] = (__bf16)v[3];
    *(bf16x2*)&sout[sb] = p0;
    *(bf16x2*)&sout[sb + 2] = p1;
  }
#pragma unroll
  for (int m = 1; m < 32; m <<= 1) {
    ssum += __shfl_xor(ssum, m, 64);
    ssq  += __shfl_xor(ssq, m, 64);
  }
  if ((lane & 31) == 0) {
    int g = wv * 2 + (q >> 1);
    atomicAdd(&st[32 + b * 8 + g], ssum);
    atomicAdd(&st[48 + b * 8 + g], ssq);
  }
}

// ---------------- k2: norm1+relu staging, qc_conv1 GEMM, stats2 ----------------
__global__ __launch_bounds__(256) void k2(
    const __bf16* __restrict__ xt, const __bf16* __restrict__ A1,
    const float* __restrict__ g1, const float* __restrict__ be1,
    const float* __restrict__ bias1,
    __bf16* __restrict__ h, float* __restrict__ st) {
  const int tx = blockIdx.x & 15, ty = blockIdx.x >> 4;  // 16 x 32 tiles of 16x8
  const int b = blockIdx.y;
  const int y0p = ty * 8, x0p = tx * 16;
  __shared__ __attribute__((aligned(16))) __bf16 tl[2][153 * 72];  // 9x17 ext tiles
  __shared__ float sc[64], sh[64];
  __shared__ float lst[16];
  const int t = threadIdx.x;

  if (t < 64) {
    int g = t >> 3;
    float mean = st[b * 8 + g] * INV_N;
    float var  = st[16 + b * 8 + g] * INV_N - mean * mean;
    float inv  = rsqrtf(var + EPSV);
    float s_ = inv * g1[t];
    sc[t] = s_;
    sh[t] = be1[t] - mean * s_;
  }
  if (t < 16) lst[t] = 0.f;
  __syncthreads();

  for (int u = t; u < 2 * 153 * 8; u += 256) {
    int cs = u / 1224;
    int rr = u - cs * 1224;
    int px = rr >> 3, cg = rr & 7;
    int ly = px / 17, lx = px - ly * 17;
    int gy = y0p + ly - cs, gx = x0p + lx - cs;
    bf16x8 v;
#pragma unroll
    for (int j = 0; j < 8; ++j) v[j] = (__bf16)0.f;
    if ((unsigned)gy < 256u && (unsigned)gx < 256u) {
      bf16x8 raw = *(const bf16x8*)&xt[(((size_t)(cs * NB + b) * WD + gy) * WD + gx) * 64 + cg * 8];
#pragma unroll
      for (int j = 0; j < 8; ++j) {
        float f = fmaf((float)raw[j], sc[cg * 8 + j], sh[cg * 8 + j]);
        v[j] = (__bf16)fmaxf(f, 0.f);
      }
    }
    *(bf16x8*)&tl[cs][px * 72 + cg * 8] = v;
  }
  __syncthreads();

  const int wv = t >> 6, lane = t & 63, ln = lane & 15, q = lane >> 4;
  const int co = wv & 1, mh = wv >> 1;
  const int q8 = q * 8;
  bf16x8 af[2][10];
#pragma unroll
  for (int m = 0; m < 2; ++m)
#pragma unroll
    for (int kk = 0; kk < 10; ++kk)
      af[m][kk] = *(const bf16x8*)&A1[(mh * 32 + m * 16 + ln) * 320 + kk * 32 + q8];

  f32x4 acc[8][2];
#pragma unroll
  for (int n = 0; n < 8; ++n)
#pragma unroll
    for (int m = 0; m < 2; ++m) acc[n][m] = (f32x4){0.f, 0.f, 0.f, 0.f};

  const __bf16* tc = tl[co];
  const __bf16* to = tl[1 - co];
#pragma unroll
  for (int n = 0; n < 8; ++n) {
    const int cpix = co ? ((n + 1) * 17 + ln + 1) : (n * 17 + ln);
    const int tb = n * 17 + ln;
    const __bf16* pc = tc + cpix * 72 + q8;
    const __bf16* p0 = to + tb * 72 + q8;
    const __bf16* p1 = to + (tb + 1) * 72 + q8;
    const __bf16* p2 = to + (tb + 17) * 72 + q8;
    const __bf16* p3 = to + (tb + 18) * 72 + q8;
    bf16x8 bb;
    bb = *(const bf16x8*)pc;        acc[n][0]=MFMA16(af[0][0],bb,acc[n][0]); acc[n][1]=MFMA16(af[1][0],bb,acc[n][1]);
    bb = *(const bf16x8*)(pc + 32); acc[n][0]=MFMA16(af[0][1],bb,acc[n][0]); acc[n][1]=MFMA16(af[1][1],bb,acc[n][1]);
    bb = *(const bf16x8*)p0;        acc[n][0]=MFMA16(af[0][2],bb,acc[n][0]); acc[n][1]=MFMA16(af[1][2],bb,acc[n][1]);
    bb = *(const bf16x8*)(p0 + 32); acc[n][0]=MFMA16(af[0][3],bb,acc[n][0]); acc[n][1]=MFMA16(af[1][3],bb,acc[n][1]);
    bb = *(const bf16x8*)p1;        acc[n][0]=MFMA16(af[0][4],bb,acc[n][0]); acc[n][1]=MFMA16(af[1][4],bb,acc[n][1]);
    bb = *(const bf16x8*)(p1 + 32); acc[n][0]=MFMA16(af[0][5],bb,acc[n][0]); acc[n][1]=MFMA16(af[1][5],bb,acc[n][1]);
    bb = *(const bf16x8*)p2;        acc[n][0]=MFMA16(af[0][6],bb,acc[n][0]); acc[n][1]=MFMA16(af[1][6],bb,acc[n][1]);
    bb = *(const bf16x8*)(p2 + 32); acc[n][0]=MFMA16(af[0][7],bb,acc[n][0]); acc[n][1]=MFMA16(af[1][7],bb,acc[n][1]);
    bb = *(const bf16x8*)p3;        acc[n][0]=MFMA16(af[0][8],bb,acc[n][0]); acc[n][1]=MFMA16(af[1][8],bb,acc[n][1]);
    bb = *(const bf16x8*)(p3 + 32); acc[n][0]=MFMA16(af[0][9],bb,acc[n][0]); acc[n][1]=MFMA16(af[1][9],bb,acc[n][1]);
  }

  float s2s[2] = {0.f, 0.f}, s2q[2] = {0.f, 0.f};
  float bia[2][4];
#pragma unroll
  for (int m = 0; m < 2; ++m)
#pragma unroll
    for (int r = 0; r < 4; ++r) bia[m][r] = bias1[mh * 32 + m * 16 + q * 4 + r];

#pragma unroll
  for (int n = 0; n < 8; ++n) {
    int gy = y0p + n;
#pragma unroll
    for (int m = 0; m < 2; ++m) {
      int ch0 = mh * 32 + m * 16 + q * 4;
      size_t hb = (((size_t)(co * NB + b) * WD + gy) * WD + x0p + ln) * 64 + ch0;
      float v[4];
#pragma unroll
      for (int r = 0; r < 4; ++r) {
        v[r] = acc[n][m][r] + bia[m][r];
        s2s[m] += v[r];
        s2q[m] = fmaf(v[r], v[r], s2q[m]);
      }
      bf16x2 p0; p0[0] = (__bf16)v[0]; p0[1] = (__bf16)v[1];
      bf16x2 p1; p1[0] = (__bf16)v[2]; p1[1] = (__bf16)v[3];
      *(bf16x2*)&h[hb] = p0;
      *(bf16x2*)&h[hb + 2] = p1;
    }
  }
#pragma unroll
  for (int m = 0; m < 2; ++m) {
    float a_ = s2s[m], c_ = s2q[m];
#pragma unroll
    for (int mk = 1; mk < 32; mk <<= 1) {
      a_ += __shfl_xor(a_, mk, 64);
      c_ += __shfl_xor(c_, mk, 64);
    }
    if ((lane & 31) == 0) {
      int g = mh * 4 + m * 2 + (q >> 1);
      atomicAdd(&lst[g], a_);
      atomicAdd(&lst[8 + g], c_);
    }
  }
  __syncthreads();
  if (t < 8) atomicAdd(&st[64 + b * 8 + t], lst[t]);
  else if (t < 16) atomicAdd(&st[80 + b * 8 + (t - 8)], lst[t]);
}

// ---------------- k3: norm2+relu staging, qc_conv2 GEMM, + skip-norm + fp32 out ----------------
__global__ __launch_bounds__(256) void k3(
    const __bf16* __restrict__ hin, const __bf16* __restrict__ A2,
    const float* __restrict__ g2, const float* __restrict__ be2,
    const float* __restrict__ bias2,
    const __bf16* __restrict__ sin_, const float* __restrict__ gsk, const float* __restrict__ bsk,
    float* __restrict__ out, const float* __restrict__ st) {
  const int tx = blockIdx.x & 15, ty = blockIdx.x >> 4;
  const int b = blockIdx.y;
  const int y0p = ty * 8, x0p = tx * 16;
  __shared__ __attribute__((aligned(16))) __bf16 tl[2][153 * 72];
  __shared__ float sc2[64], sh2[64], scS[64], shS[64];
  const int t = threadIdx.x;

  if (t < 64) {
    int g = t >> 3;
    float m2 = st[64 + b * 8 + g] * INV_N;
    float v2 = st[80 + b * 8 + g] * INV_N - m2 * m2;
    float i2 = rsqrtf(v2 + EPSV);
    float s2_ = i2 * g2[t];
    sc2[t] = s2_;
    sh2[t] = be2[t] - m2 * s2_;
    float mS = st[32 + b * 8 + g] * INV_N;
    float vS = st[48 + b * 8 + g] * INV_N - mS * mS;
    float iS = rsqrtf(vS + EPSV);
    float sS_ = iS * gsk[t];
    scS[t] = sS_;
    shS[t] = bsk[t] - mS * sS_;
  }
  __syncthreads();

  for (int u = t; u < 2 * 153 * 8; u += 256) {
    int cs = u / 1224;
    int rr = u - cs * 1224;
    int px = rr >> 3, cg = rr & 7;
    int ly = px / 17, lx = px - ly * 17;
    int gy = y0p + ly - cs, gx = x0p + lx - cs;
    bf16x8 v;
#pragma unroll
    for (int j = 0; j < 8; ++j) v[j] = (__bf16)0.f;
    if ((unsigned)gy < 256u && (unsigned)gx < 256u) {
      bf16x8 raw = *(const bf16x8*)&hin[(((size_t)(cs * NB + b) * WD + gy) * WD + gx) * 64 + cg * 8];
#pragma unroll
      for (int j = 0; j < 8; ++j) {
        float f = fmaf((float)raw[j], sc2[cg * 8 + j], sh2[cg * 8 + j]);
        v[j] = (__bf16)fmaxf(f, 0.f);
      }
    }
    *(bf16x8*)&tl[cs][px * 72 + cg * 8] = v;
  }
  __syncthreads();

  const int wv = t >> 6, lane = t & 63, ln = lane & 15, q = lane >> 4;
  const int co = wv & 1, mh = wv >> 1;
  const int q8 = q * 8;
  bf16x8 af[2][10];
#pragma unroll
  for (int m = 0; m < 2; ++m)
#pragma unroll
    for (int kk = 0; kk < 10; ++kk)
      af[m][kk] = *(const bf16x8*)&A2[(mh * 32 + m * 16 + ln) * 320 + kk * 32 + q8];

  f32x4 acc[8][2];
#pragma unroll
  for (int n = 0; n < 8; ++n)
#pragma unroll
    for (int m = 0; m < 2; ++m) acc[n][m] = (f32x4){0.f, 0.f, 0.f, 0.f};

  const __bf16* tc = tl[co];
  const __bf16* to = tl[1 - co];
#pragma unroll
  for (int n = 0; n < 8; ++n) {
    const int cpix = co ? ((n + 1) * 17 + ln + 1) : (n * 17 + ln);
    const int tb = n * 17 + ln;
    const __bf16* pc = tc + cpix * 72 + q8;
    const __bf16* p0 = to + tb * 72 + q8;
    const __bf16* p1 = to + (tb + 1) * 72 + q8;
    const __bf16* p2 = to + (tb + 17) * 72 + q8;
    const __bf16* p3 = to + (tb + 18) * 72 + q8;
    bf16x8 bb;
    bb = *(const bf16x8*)pc;        acc[n][0]=MFMA16(af[0][0],bb,acc[n][0]); acc[n][1]=MFMA16(af[1][0],bb,acc[n][1]);
    bb = *(const bf16x8*)(pc + 32); acc[n][0]=MFMA16(af[0][1],bb,acc[n][0]); acc[n][1]=MFMA16(af[1][1],bb,acc[n][1]);
    bb = *(const bf16x8*)p0;        acc[n][0]=MFMA16(af[0][2],bb,acc[n][0]); acc[n][1]=MFMA16(af[1][2],bb,acc[n][1]);
    bb = *(const bf16x8*)(p0 + 32); acc[n][0]=MFMA16(af[0][3],bb,acc[n][0]); acc[n][1]=MFMA16(af[1][3],bb,acc[n][1]);
    bb = *(const bf16x8*)p1;        acc[n][0]=MFMA16(af[0][4],bb,acc[n][0]); acc[n][1]=MFMA16(af[1][4],bb,acc[n][1]);
    bb = *(const bf16x8*)(p1 + 32); acc[n][0]=MFMA16(af[0][5],bb,acc[n][0]); acc[n][1]=MFMA16(af[1][5],bb,acc[n][1]);
    bb = *(const bf16x8*)p2;        acc[n][0]=MFMA16(af[0][6],bb,acc[n][0]); acc[n][1]=MFMA16(af[1][6],bb,acc[n][1]);
    bb = *(const bf16x8*)(p2 + 32); acc[n][0]=MFMA16(af[0][7],bb,acc[n][0]); acc[n][1]=MFMA16(af[1][7],bb,acc[n][1]);
    bb = *(const bf16x8*)p3;        acc[n][0]=MFMA16(af[0][8],bb,acc[n][0]); acc[n][1]=MFMA16(af[1][8],bb,acc[n][1]);
    bb = *(const bf16x8*)(p3 + 32); acc[n][0]=MFMA16(af[0][9],bb,acc[n][0]); acc[n][1]=MFMA16(af[1][9],bb,acc[n][1]);
  }

  float bia[2][4], sA[2][4], sB[2][4];
#pragma unroll
  for (int m = 0; m < 2; ++m)
#pragma unroll
    for (int r = 0; r < 4; ++r) {
      int ch = mh * 32 + m * 16 + q * 4 + r;
      bia[m][r] = bias2[ch];
      sA[m][r] = scS[ch];
      sB[m][r] = shS[ch];
    }

#pragma unroll
  for (int n = 0; n < 8; ++n) {
    int gy = y0p + n;
#pragma unroll
    for (int m = 0; m < 2; ++m) {
      int ch0 = mh * 32 + m * 16 + q * 4;
      size_t sb = (((size_t)(co * NB + b) * WD + gy) * WD + x0p + ln) * 64 + ch0;
      bf16x2 sv0 = *(const bf16x2*)&sin_[sb];
      bf16x2 sv1 = *(const bf16x2*)&sin_[sb + 2];
      float sraw[4] = {(float)sv0[0], (float)sv0[1], (float)sv1[0], (float)sv1[1]};
      size_t ob = ((size_t)(co * NB + b) * 64 + ch0) * HW + (size_t)gy * WD + x0p + ln;
#pragma unroll
      for (int r = 0; r < 4; ++r) {
        float v = acc[n][m][r] + bia[m][r] + fmaf(sraw[r], sA[m][r], sB[m][r]);
        out[ob + (size_t)r * HW] = v;
      }
    }
  }
}

extern "C" void kernel_launch(void* const* d_in, const int* in_sizes, int n_in,
                              void* d_out, int out_size, void* d_ws, size_t ws_size,
                              hipStream_t stream) {
  (void)in_sizes; (void)n_in; (void)out_size; (void)ws_size;
  const float* x0    = (const float*)d_in[0];
  const float* x1    = (const float*)d_in[1];
  const float* g1    = (const float*)d_in[2];
  const float* b1    = (const float*)d_in[3];
  const float* w1c   = (const float*)d_in[4];
  const float* w1k   = (const float*)d_in[5];
  const float* bias1 = (const float*)d_in[6];
  const float* g2    = (const float*)d_in[7];
  const float* b2    = (const float*)d_in[8];
  const float* w2c   = (const float*)d_in[9];
  const float* w2k   = (const float*)d_in[10];
  const float* bias2 = (const float*)d_in[11];
  const float* wsk   = (const float*)d_in[12];
  const float* bsk   = (const float*)d_in[13];
  const float* gsk   = (const float*)d_in[14];
  const float* besk  = (const float*)d_in[15];

  char* ws = (char*)d_ws;
  float*  st = (float*)(ws + OFF_STATS);
  __bf16* A1 = (__bf16*)(ws + OFF_A1);
  __bf16* A2 = (__bf16*)(ws + OFF_A2);
  __bf16* xt = (__bf16*)(ws + OFF_XT);
  __bf16* s  = (__bf16*)(ws + OFF_S);
  __bf16* h  = (__bf16*)(ws + OFF_H);

  hipMemsetAsync(st, 0, 96 * sizeof(float), stream);
  k_prep<<<2, 256, 0, stream>>>(w1c, w1k, w2c, w2k, A1, A2);
  k1<<<dim3(256, 2, 2), 256, 0, stream>>>(x0, x1, wsk, bsk, xt, s, st);
  k2<<<dim3(512, 2), 256, 0, stream>>>(xt, A1, g1, b1, bias1, h, st);
  k3<<<dim3(512, 2), 256, 0, stream>>>(h, A2, g2, b2, bias2, s, gsk, besk, (float*)d_out, st);
}

// Round 5
// 329.389 us; speedup vs baseline: 2.1065x; 2.1065x over previous
//
#include <hip/hip_runtime.h>

typedef __attribute__((ext_vector_type(8))) __bf16 bf16x8;
typedef __attribute__((ext_vector_type(2))) __bf16 bf16x2;
typedef __attribute__((ext_vector_type(4))) float f32x4;

#define MFMA16(a,b,c) __builtin_amdgcn_mfma_f32_16x16x32_bf16(a,b,c,0,0,0)

static constexpr int HW = 65536;   // 256*256
static constexpr int WD = 256;
static constexpr int NB = 2;       // batch
static constexpr double INV_N = 1.0 / 1048576.0;   // 8ch*65536px*2cosets
static constexpr float EPSV = 1e-5f;

// workspace layout (bytes)
static constexpr size_t OFF_P1  = 0;                   // 1024 blocks x 32 f32 partials (stats1+skip)
static constexpr size_t OFF_P2  = 131072;              // 1024 blocks x 16 f32 partials (stats2)
static constexpr size_t OFF_NRM = 196608;              // 768 f32: nrm1[2][2][64], nrmS(+256), nrm2(+512)
static constexpr size_t OFF_A1  = 200704;              // 20480 bf16
static constexpr size_t OFF_A2  = OFF_A1 + 40960;
static constexpr size_t OFF_XT  = OFF_A2 + 40960;
static constexpr size_t SZ_T    = (size_t)2 * NB * HW * 64 * 2;  // 32 MiB
static constexpr size_t OFF_S   = OFF_XT + SZ_T;
static constexpr size_t OFF_H   = OFF_S + SZ_T;

// ---------------- weight prep: A[o][k], k: [0,64)=center, [64+t*64+c]=tap t ----------------
__global__ void k_prep(const float* __restrict__ wc1, const float* __restrict__ wk1,
                       const float* __restrict__ wc2, const float* __restrict__ wk2,
                       __bf16* __restrict__ A1, __bf16* __restrict__ A2) {
  const int stage = blockIdx.x;
  const float* wc = stage ? wc2 : wc1;
  const float* wk = stage ? wk2 : wk1;
  __bf16* A = stage ? A2 : A1;
  for (int idx = threadIdx.x; idx < 64 * 320; idx += blockDim.x) {
    int o = idx / 320, k = idx - o * 320;
    float v;
    if (k < 64) v = wc[o * 64 + k];
    else {
      int t = (k - 64) >> 6;
      int c = k & 63;
      v = wk[(o * 64 + c) * 4 + t];
    }
    A[idx] = (__bf16)v;
  }
}

// ---------------- k1: stats1 partials + skip GEMM + NHWC bf16 transpose ----------------
__global__ __launch_bounds__(256) void k1(
    const float* __restrict__ x0, const float* __restrict__ x1,
    const float* __restrict__ wskip, const float* __restrict__ bskip,
    __bf16* __restrict__ xt, __bf16* __restrict__ sout, float* __restrict__ p1) {
  const int row = blockIdx.x;   // 0..255 (H row)
  const int b   = blockIdx.y;
  const int co  = blockIdx.z;
  const float* x = co ? x1 : x0;
  __shared__ __attribute__((aligned(16))) __bf16 tile[256 * 72];
  __shared__ float redp[64];   // [wv*16 + kind*8 + g] stats1 per-wave partials
  __shared__ float reds[16];   // skip stats: [kind*8 + g]
  const int t = threadIdx.x;    // = pixel x within row
  const int wv = t >> 6, lane = t & 63;

  const float* xbase = x + (size_t)b * 64 * HW + (size_t)row * WD + t;
  __bf16* xtbase = xt + (((size_t)(co * NB + b) * HW) + (size_t)row * WD + t) * 64;

  for (int cg = 0; cg < 8; ++cg) {
    bf16x8 v;
    float sum = 0.f, sq = 0.f;
#pragma unroll
    for (int j = 0; j < 8; ++j) {
      float f = xbase[(size_t)(cg * 8 + j) * HW];
      v[j] = (__bf16)f;
      sum += f;
      sq = fmaf(f, f, sq);
    }
    *(bf16x8*)&tile[t * 72 + cg * 8] = v;
    *(bf16x8*)&xtbase[cg * 8] = v;
#pragma unroll
    for (int m = 1; m < 64; m <<= 1) {
      sum += __shfl_xor(sum, m, 64);
      sq  += __shfl_xor(sq, m, 64);
    }
    if (lane == 0) {
      redp[wv * 16 + cg] = sum;
      redp[wv * 16 + 8 + cg] = sq;
    }
  }
  __syncthreads();

  const int ln = lane & 15, q = lane >> 4;
  const int ch0 = wv * 16 + q * 4;
  bf16x8 a0, a1;
#pragma unroll
  for (int j = 0; j < 8; ++j) {
    a0[j] = (__bf16)wskip[(wv * 16 + ln) * 64 + q * 8 + j];
    a1[j] = (__bf16)wskip[(wv * 16 + ln) * 64 + 32 + q * 8 + j];
  }
  float bia[4];
#pragma unroll
  for (int r = 0; r < 4; ++r) bia[r] = bskip[ch0 + r];

  float ssum = 0.f, ssq = 0.f;
  for (int n = 0; n < 16; ++n) {
    f32x4 acc = {0.f, 0.f, 0.f, 0.f};
    bf16x8 b0 = *(const bf16x8*)&tile[(n * 16 + ln) * 72 + q * 8];
    bf16x8 b1 = *(const bf16x8*)&tile[(n * 16 + ln) * 72 + 32 + q * 8];
    acc = MFMA16(a0, b0, acc);
    acc = MFMA16(a1, b1, acc);
    float v[4];
#pragma unroll
    for (int r = 0; r < 4; ++r) {
      v[r] = acc[r] + bia[r];
      ssum += v[r];
      ssq = fmaf(v[r], v[r], ssq);
    }
    size_t sb = (((size_t)(co * NB + b) * HW) + (size_t)row * WD + n * 16 + ln) * 64 + ch0;
    bf16x2 p0; p0[0] = (__bf16)v[0]; p0[1] = (__bf16)v[1];
    bf16x2 p1v; p1v[0] = (__bf16)v[2]; p1v[1] = (__bf16)v[3];
    *(bf16x2*)&sout[sb] = p0;
    *(bf16x2*)&sout[sb + 2] = p1v;
  }
#pragma unroll
  for (int m = 1; m < 32; m <<= 1) {
    ssum += __shfl_xor(ssum, m, 64);
    ssq  += __shfl_xor(ssq, m, 64);
  }
  if (lane == 0)  { reds[2 * wv] = ssum;     reds[8 + 2 * wv] = ssq; }
  if (lane == 32) { reds[2 * wv + 1] = ssum; reds[8 + 2 * wv + 1] = ssq; }

  __syncthreads();
  if (t < 32) {
    float val;
    if (t < 16) val = redp[t] + redp[16 + t] + redp[32 + t] + redp[48 + t];
    else val = reds[t - 16];
    const int bf1 = (co * 2 + b) * 256 + row;
    p1[(size_t)bf1 * 32 + t] = val;
  }
}

// ---------------- k_r1: reduce p1 -> nrm1 + nrmS (scale/shift per b,ch), f64 accum ----------------
__global__ __launch_bounds__(256) void k_r1(
    const float* __restrict__ p1, const float* __restrict__ g1, const float* __restrict__ be1,
    const float* __restrict__ gsk, const float* __restrict__ besk, float* __restrict__ nrm) {
  const int t = threadIdx.x;
  __shared__ double red[64];
  const int sid = t >> 2, sub = t & 3;           // sid = which*32 + b*16 + kind*8 + g
  const int which = sid >> 5, b = (sid >> 4) & 1, kg = sid & 15;
  const int col = which * 16 + kg;
  double v = 0.0;
  for (int j = sub; j < 512; j += 4) {
    int co = j >> 8, rr = j & 255;
    v += (double)p1[((size_t)(co * 2 + b) * 256 + rr) * 32 + col];
  }
  v += __shfl_xor(v, 1, 64);
  v += __shfl_xor(v, 2, 64);
  if (sub == 0) red[sid] = v;
  __syncthreads();
  {
    int half = t >> 7;           // 0: nrm1, 1: nrmS
    int b2 = (t >> 6) & 1, ch = t & 63, g = ch >> 3;
    int base = half * 32 + b2 * 16;
    double mean = red[base + g] * INV_N;
    double var  = red[base + 8 + g] * INV_N - mean * mean;
    float inv  = rsqrtf((float)var + EPSV);
    float ga = half ? gsk[ch] : g1[ch];
    float be = half ? besk[ch] : be1[ch];   // FIX: skip GN beta = beta_skip, NOT bias_skip
    float sc = inv * ga;
    nrm[half * 256 + b2 * 128 + ch] = sc;
    nrm[half * 256 + b2 * 128 + 64 + ch] = be - (float)mean * sc;
  }
}

// ---------------- k2: norm1+relu staging, qc_conv1 GEMM, stats2 partials ----------------
__global__ __launch_bounds__(256) void k2(
    const __bf16* __restrict__ xt, const __bf16* __restrict__ A1,
    const float* __restrict__ nrm, const float* __restrict__ bias1,
    __bf16* __restrict__ h, float* __restrict__ p2) {
  const int tx = blockIdx.x & 15, ty = blockIdx.x >> 4;  // 16 x 32 tiles of 16x8
  const int b = blockIdx.y;
  const int y0p = ty * 8, x0p = tx * 16;
  __shared__ __attribute__((aligned(16))) __bf16 tl[2][153 * 72];  // 9x17 ext tiles
  __shared__ float sc[64], sh[64];
  __shared__ float lst[16];
  const int t = threadIdx.x;

  if (t < 64) {
    sc[t] = nrm[b * 128 + t];
    sh[t] = nrm[b * 128 + 64 + t];
  }
  if (t < 16) lst[t] = 0.f;
  __syncthreads();

  for (int u = t; u < 2 * 153 * 8; u += 256) {
    int cs = u / 1224;
    int rr = u - cs * 1224;
    int px = rr >> 3, cg = rr & 7;
    int ly = px / 17, lx = px - ly * 17;
    int gy = y0p + ly - cs, gx = x0p + lx - cs;
    bf16x8 v;
#pragma unroll
    for (int j = 0; j < 8; ++j) v[j] = (__bf16)0.f;
    if ((unsigned)gy < 256u && (unsigned)gx < 256u) {
      bf16x8 raw = *(const bf16x8*)&xt[(((size_t)(cs * NB + b) * WD + gy) * WD + gx) * 64 + cg * 8];
#pragma unroll
      for (int j = 0; j < 8; ++j) {
        float f = fmaf((float)raw[j], sc[cg * 8 + j], sh[cg * 8 + j]);
        v[j] = (__bf16)fmaxf(f, 0.f);
      }
    }
    *(bf16x8*)&tl[cs][px * 72 + cg * 8] = v;
  }
  __syncthreads();

  const int wv = t >> 6, lane = t & 63, ln = lane & 15, q = lane >> 4;
  const int co = wv & 1, mh = wv >> 1;
  const int q8 = q * 8;
  bf16x8 af[2][10];
#pragma unroll
  for (int m = 0; m < 2; ++m)
#pragma unroll
    for (int kk = 0; kk < 10; ++kk)
      af[m][kk] = *(const bf16x8*)&A1[(mh * 32 + m * 16 + ln) * 320 + kk * 32 + q8];

  f32x4 acc[8][2];
#pragma unroll
  for (int n = 0; n < 8; ++n)
#pragma unroll
    for (int m = 0; m < 2; ++m) acc[n][m] = (f32x4){0.f, 0.f, 0.f, 0.f};

  const __bf16* tc = tl[co];
  const __bf16* to = tl[1 - co];
#pragma unroll
  for (int n = 0; n < 8; ++n) {
    const int cpix = co ? ((n + 1) * 17 + ln + 1) : (n * 17 + ln);
    const int tb = n * 17 + ln;
    const __bf16* pc = tc + cpix * 72 + q8;
    const __bf16* p0 = to + tb * 72 + q8;
    const __bf16* p1p = to + (tb + 1) * 72 + q8;
    const __bf16* p2p = to + (tb + 17) * 72 + q8;
    const __bf16* p3 = to + (tb + 18) * 72 + q8;
    bf16x8 bb;
    bb = *(const bf16x8*)pc;         acc[n][0]=MFMA16(af[0][0],bb,acc[n][0]); acc[n][1]=MFMA16(af[1][0],bb,acc[n][1]);
    bb = *(const bf16x8*)(pc + 32);  acc[n][0]=MFMA16(af[0][1],bb,acc[n][0]); acc[n][1]=MFMA16(af[1][1],bb,acc[n][1]);
    bb = *(const bf16x8*)p0;         acc[n][0]=MFMA16(af[0][2],bb,acc[n][0]); acc[n][1]=MFMA16(af[1][2],bb,acc[n][1]);
    bb = *(const bf16x8*)(p0 + 32);  acc[n][0]=MFMA16(af[0][3],bb,acc[n][0]); acc[n][1]=MFMA16(af[1][3],bb,acc[n][1]);
    bb = *(const bf16x8*)p1p;        acc[n][0]=MFMA16(af[0][4],bb,acc[n][0]); acc[n][1]=MFMA16(af[1][4],bb,acc[n][1]);
    bb = *(const bf16x8*)(p1p + 32); acc[n][0]=MFMA16(af[0][5],bb,acc[n][0]); acc[n][1]=MFMA16(af[1][5],bb,acc[n][1]);
    bb = *(const bf16x8*)p2p;        acc[n][0]=MFMA16(af[0][6],bb,acc[n][0]); acc[n][1]=MFMA16(af[1][6],bb,acc[n][1]);
    bb = *(const bf16x8*)(p2p + 32); acc[n][0]=MFMA16(af[0][7],bb,acc[n][0]); acc[n][1]=MFMA16(af[1][7],bb,acc[n][1]);
    bb = *(const bf16x8*)p3;         acc[n][0]=MFMA16(af[0][8],bb,acc[n][0]); acc[n][1]=MFMA16(af[1][8],bb,acc[n][1]);
    bb = *(const bf16x8*)(p3 + 32);  acc[n][0]=MFMA16(af[0][9],bb,acc[n][0]); acc[n][1]=MFMA16(af[1][9],bb,acc[n][1]);
  }

  float s2s[2] = {0.f, 0.f}, s2q[2] = {0.f, 0.f};
  float bia[2][4];
#pragma unroll
  for (int m = 0; m < 2; ++m)
#pragma unroll
    for (int r = 0; r < 4; ++r) bia[m][r] = bias1[mh * 32 + m * 16 + q * 4 + r];

#pragma unroll
  for (int n = 0; n < 8; ++n) {
    int gy = y0p + n;
#pragma unroll
    for (int m = 0; m < 2; ++m) {
      int ch0 = mh * 32 + m * 16 + q * 4;
      size_t hb = (((size_t)(co * NB + b) * WD + gy) * WD + x0p + ln) * 64 + ch0;
      float v[4];
#pragma unroll
      for (int r = 0; r < 4; ++r) {
        v[r] = acc[n][m][r] + bia[m][r];
        s2s[m] += v[r];
        s2q[m] = fmaf(v[r], v[r], s2q[m]);
      }
      bf16x2 p0; p0[0] = (__bf16)v[0]; p0[1] = (__bf16)v[1];
      bf16x2 p1v; p1v[0] = (__bf16)v[2]; p1v[1] = (__bf16)v[3];
      *(bf16x2*)&h[hb] = p0;
      *(bf16x2*)&h[hb + 2] = p1v;
    }
  }
#pragma unroll
  for (int m = 0; m < 2; ++m) {
    float a_ = s2s[m], c_ = s2q[m];
#pragma unroll
    for (int mk = 1; mk < 32; mk <<= 1) {
      a_ += __shfl_xor(a_, mk, 64);
      c_ += __shfl_xor(c_, mk, 64);
    }
    if ((lane & 31) == 0) {
      int g = mh * 4 + m * 2 + (q >> 1);
      atomicAdd(&lst[g], a_);
      atomicAdd(&lst[8 + g], c_);
    }
  }
  __syncthreads();
  if (t < 16) p2[((size_t)b * 512 + blockIdx.x) * 16 + t] = lst[t];
}

// ---------------- k_r2: reduce p2 -> nrm2, f64 accum ----------------
__global__ __launch_bounds__(256) void k_r2(
    const float* __restrict__ p2, const float* __restrict__ g2, const float* __restrict__ be2,
    float* __restrict__ nrm) {
  const int t = threadIdx.x;
  __shared__ double red[32];
  const int sid = t >> 3, sub = t & 7;   // sid = b*16 + kind*8 + g
  const int b = sid >> 4, col = sid & 15;
  double v = 0.0;
  for (int j = sub; j < 512; j += 8)
    v += (double)p2[((size_t)b * 512 + j) * 16 + col];
  v += __shfl_xor(v, 1, 64);
  v += __shfl_xor(v, 2, 64);
  v += __shfl_xor(v, 4, 64);
  if (sub == 0) red[sid] = v;
  __syncthreads();
  if (t < 128) {
    int b2 = t >> 6, ch = t & 63, g = ch >> 3;
    double mean = red[b2 * 16 + g] * INV_N;
    double var  = red[b2 * 16 + 8 + g] * INV_N - mean * mean;
    float inv  = rsqrtf((float)var + EPSV);
    float sc = inv * g2[ch];
    nrm[512 + b2 * 128 + ch] = sc;
    nrm[512 + b2 * 128 + 64 + ch] = be2[ch] - (float)mean * sc;
  }
}

// ---------------- k3: norm2+relu staging, qc_conv2 GEMM, + skip-norm + fp32 out ----------------
__global__ __launch_bounds__(256) void k3(
    const __bf16* __restrict__ hin, const __bf16* __restrict__ A2,
    const float* __restrict__ nrm, const float* __restrict__ bias2,
    const __bf16* __restrict__ sin_, float* __restrict__ out) {
  const int tx = blockIdx.x & 15, ty = blockIdx.x >> 4;
  const int b = blockIdx.y;
  const int y0p = ty * 8, x0p = tx * 16;
  __shared__ __attribute__((aligned(16))) __bf16 tl[2][153 * 72];
  __shared__ float sc2[64], sh2[64], scS[64], shS[64];
  const int t = threadIdx.x;

  if (t < 64) {
    sc2[t] = nrm[512 + b * 128 + t];
    sh2[t] = nrm[512 + b * 128 + 64 + t];
    scS[t] = nrm[256 + b * 128 + t];
    shS[t] = nrm[256 + b * 128 + 64 + t];
  }
  __syncthreads();

  for (int u = t; u < 2 * 153 * 8; u += 256) {
    int cs = u / 1224;
    int rr = u - cs * 1224;
    int px = rr >> 3, cg = rr & 7;
    int ly = px / 17, lx = px - ly * 17;
    int gy = y0p + ly - cs, gx = x0p + lx - cs;
    bf16x8 v;
#pragma unroll
    for (int j = 0; j < 8; ++j) v[j] = (__bf16)0.f;
    if ((unsigned)gy < 256u && (unsigned)gx < 256u) {
      bf16x8 raw = *(const bf16x8*)&hin[(((size_t)(cs * NB + b) * WD + gy) * WD + gx) * 64 + cg * 8];
#pragma unroll
      for (int j = 0; j < 8; ++j) {
        float f = fmaf((float)raw[j], sc2[cg * 8 + j], sh2[cg * 8 + j]);
        v[j] = (__bf16)fmaxf(f, 0.f);
      }
    }
    *(bf16x8*)&tl[cs][px * 72 + cg * 8] = v;
  }
  __syncthreads();

  const int wv = t >> 6, lane = t & 63, ln = lane & 15, q = lane >> 4;
  const int co = wv & 1, mh = wv >> 1;
  const int q8 = q * 8;
  bf16x8 af[2][10];
#pragma unroll
  for (int m = 0; m < 2; ++m)
#pragma unroll
    for (int kk = 0; kk < 10; ++kk)
      af[m][kk] = *(const bf16x8*)&A2[(mh * 32 + m * 16 + ln) * 320 + kk * 32 + q8];

  f32x4 acc[8][2];
#pragma unroll
  for (int n = 0; n < 8; ++n)
#pragma unroll
    for (int m = 0; m < 2; ++m) acc[n][m] = (f32x4){0.f, 0.f, 0.f, 0.f};

  const __bf16* tc = tl[co];
  const __bf16* to = tl[1 - co];
#pragma unroll
  for (int n = 0; n < 8; ++n) {
    const int cpix = co ? ((n + 1) * 17 + ln + 1) : (n * 17 + ln);
    const int tb = n * 17 + ln;
    const __bf16* pc = tc + cpix * 72 + q8;
    const __bf16* p0 = to + tb * 72 + q8;
    const __bf16* p1p = to + (tb + 1) * 72 + q8;
    const __bf16* p2p = to + (tb + 17) * 72 + q8;
    const __bf16* p3 = to + (tb + 18) * 72 + q8;
    bf16x8 bb;
    bb = *(const bf16x8*)pc;         acc[n][0]=MFMA16(af[0][0],bb,acc[n][0]); acc[n][1]=MFMA16(af[1][0],bb,acc[n][1]);
    bb = *(const bf16x8*)(pc + 32);  acc[n][0]=MFMA16(af[0][1],bb,acc[n][0]); acc[n][1]=MFMA16(af[1][1],bb,acc[n][1]);
    bb = *(const bf16x8*)p0;         acc[n][0]=MFMA16(af[0][2],bb,acc[n][0]); acc[n][1]=MFMA16(af[1][2],bb,acc[n][1]);
    bb = *(const bf16x8*)(p0 + 32);  acc[n][0]=MFMA16(af[0][3],bb,acc[n][0]); acc[n][1]=MFMA16(af[1][3],bb,acc[n][1]);
    bb = *(const bf16x8*)p1p;        acc[n][0]=MFMA16(af[0][4],bb,acc[n][0]); acc[n][1]=MFMA16(af[1][4],bb,acc[n][1]);
    bb = *(const bf16x8*)(p1p + 32); acc[n][0]=MFMA16(af[0][5],bb,acc[n][0]); acc[n][1]=MFMA16(af[1][5],bb,acc[n][1]);
    bb = *(const bf16x8*)p2p;        acc[n][0]=MFMA16(af[0][6],bb,acc[n][0]); acc[n][1]=MFMA16(af[1][6],bb,acc[n][1]);
    bb = *(const bf16x8*)(p2p + 32); acc[n][0]=MFMA16(af[0][7],bb,acc[n][0]); acc[n][1]=MFMA16(af[1][7],bb,acc[n][1]);
    bb = *(const bf16x8*)p3;         acc[n][0]=MFMA16(af[0][8],bb,acc[n][0]); acc[n][1]=MFMA16(af[1][8],bb,acc[n][1]);
    bb = *(const bf16x8*)(p3 + 32);  acc[n][0]=MFMA16(af[0][9],bb,acc[n][0]); acc[n][1]=MFMA16(af[1][9],bb,acc[n][1]);
  }

  float bia[2][4], sA[2][4], sB[2][4];
#pragma unroll
  for (int m = 0; m < 2; ++m)
#pragma unroll
    for (int r = 0; r < 4; ++r) {
      int ch = mh * 32 + m * 16 + q * 4 + r;
      bia[m][r] = bias2[ch];
      sA[m][r] = scS[ch];
      sB[m][r] = shS[ch];
    }

#pragma unroll
  for (int n = 0; n < 8; ++n) {
    int gy = y0p + n;
#pragma unroll
    for (int m = 0; m < 2; ++m) {
      int ch0 = mh * 32 + m * 16 + q * 4;
      size_t sb = (((size_t)(co * NB + b) * WD + gy) * WD + x0p + ln) * 64 + ch0;
      bf16x2 sv0 = *(const bf16x2*)&sin_[sb];
      bf16x2 sv1 = *(const bf16x2*)&sin_[sb + 2];
      float sraw[4] = {(float)sv0[0], (float)sv0[1], (float)sv1[0], (float)sv1[1]};
      size_t ob = ((size_t)(co * NB + b) * 64 + ch0) * HW + (size_t)gy * WD + x0p + ln;
#pragma unroll
      for (int r = 0; r < 4; ++r) {
        float v = acc[n][m][r] + bia[m][r] + fmaf(sraw[r], sA[m][r], sB[m][r]);
        out[ob + (size_t)r * HW] = v;
      }
    }
  }
}

extern "C" void kernel_launch(void* const* d_in, const int* in_sizes, int n_in,
                              void* d_out, int out_size, void* d_ws, size_t ws_size,
                              hipStream_t stream) {
  (void)in_sizes; (void)n_in; (void)out_size; (void)ws_size;
  const float* x0    = (const float*)d_in[0];
  const float* x1    = (const float*)d_in[1];
  const float* g1    = (const float*)d_in[2];
  const float* b1    = (const float*)d_in[3];
  const float* w1c   = (const float*)d_in[4];
  const float* w1k   = (const float*)d_in[5];
  const float* bias1 = (const float*)d_in[6];
  const float* g2    = (const float*)d_in[7];
  const float* b2    = (const float*)d_in[8];
  const float* w2c   = (const float*)d_in[9];
  const float* w2k   = (const float*)d_in[10];
  const float* bias2 = (const float*)d_in[11];
  const float* wsk   = (const float*)d_in[12];
  const float* bsk   = (const float*)d_in[13];
  const float* gsk   = (const float*)d_in[14];
  const float* besk  = (const float*)d_in[15];

  char* ws = (char*)d_ws;
  float*  p1 = (float*)(ws + OFF_P1);
  float*  p2 = (float*)(ws + OFF_P2);
  float*  nrm = (float*)(ws + OFF_NRM);
  __bf16* A1 = (__bf16*)(ws + OFF_A1);
  __bf16* A2 = (__bf16*)(ws + OFF_A2);
  __bf16* xt = (__bf16*)(ws + OFF_XT);
  __bf16* s  = (__bf16*)(ws + OFF_S);
  __bf16* h  = (__bf16*)(ws + OFF_H);

  k_prep<<<2, 256, 0, stream>>>(w1c, w1k, w2c, w2k, A1, A2);
  k1<<<dim3(256, 2, 2), 256, 0, stream>>>(x0, x1, wsk, bsk, xt, s, p1);
  k_r1<<<1, 256, 0, stream>>>(p1, g1, b1, gsk, besk, nrm);   // FIX: pass beta_skip (besk), not bias_skip (bsk)
  k2<<<dim3(512, 2), 256, 0, stream>>>(xt, A1, nrm, bias1, h, p2);
  k_r2<<<1, 256, 0, stream>>>(p2, g2, b2, nrm);
  k3<<<dim3(512, 2), 256, 0, stream>>>(h, A2, nrm, bias2, s, (float*)d_out);
}

// Round 6
// 328.201 us; speedup vs baseline: 2.1141x; 1.0036x over previous
//
#include <hip/hip_runtime.h>

typedef __attribute__((ext_vector_type(8))) __bf16 bf16x8;
typedef __attribute__((ext_vector_type(4))) __bf16 bf16x4;
typedef __attribute__((ext_vector_type(2))) __bf16 bf16x2;
typedef __attribute__((ext_vector_type(4))) float f32x4;

#define MFMA16(a,b,c) __builtin_amdgcn_mfma_f32_16x16x32_bf16(a,b,c,0,0,0)

static constexpr int HW = 65536;   // 256*256
static constexpr int WD = 256;
static constexpr int NB = 2;       // batch
static constexpr double INV_N = 1.0 / 1048576.0;   // 8ch*65536px*2cosets
static constexpr float EPSV = 1e-5f;

// workspace layout (bytes)
static constexpr size_t OFF_P1  = 0;                   // 1024 blocks x 32 f32 partials (stats1+skip)
static constexpr size_t OFF_P2  = 131072;              // 1024 blocks x 16 f32 partials (stats2)
static constexpr size_t OFF_NRM = 196608;              // 768 f32: nrm1[2][2][64], nrmS(+256), nrm2(+512)
static constexpr size_t OFF_A1  = 200704;              // 20480 bf16
static constexpr size_t OFF_A2  = OFF_A1 + 40960;
static constexpr size_t OFF_XT  = OFF_A2 + 40960;
static constexpr size_t SZ_T    = (size_t)2 * NB * HW * 64 * 2;  // 32 MiB
static constexpr size_t OFF_S   = OFF_XT + SZ_T;
static constexpr size_t OFF_H   = OFF_S + SZ_T;

// ---------------- weight prep: A[o][k], k: [0,64)=center, [64+t*64+c]=tap t ----------------
__global__ void k_prep(const float* __restrict__ wc1, const float* __restrict__ wk1,
                       const float* __restrict__ wc2, const float* __restrict__ wk2,
                       __bf16* __restrict__ A1, __bf16* __restrict__ A2) {
  const int stage = blockIdx.x;
  const float* wc = stage ? wc2 : wc1;
  const float* wk = stage ? wk2 : wk1;
  __bf16* A = stage ? A2 : A1;
  for (int idx = threadIdx.x; idx < 64 * 320; idx += blockDim.x) {
    int o = idx / 320, k = idx - o * 320;
    float v;
    if (k < 64) v = wc[o * 64 + k];
    else {
      int t = (k - 64) >> 6;
      int c = k & 63;
      v = wk[(o * 64 + c) * 4 + t];
    }
    A[idx] = (__bf16)v;
  }
}

// ---------------- k1: stats1 partials + skip GEMM + NHWC bf16 transpose ----------------
// s layout (fragment-native): [(co*NB+b)][pxhi=px/16][ch/4][px&15][ch&3], bf16
__global__ __launch_bounds__(256) void k1(
    const float* __restrict__ x0, const float* __restrict__ x1,
    const float* __restrict__ wskip, const float* __restrict__ bskip,
    __bf16* __restrict__ xt, __bf16* __restrict__ sout, float* __restrict__ p1) {
  const int row = blockIdx.x;   // 0..255 (H row)
  const int b   = blockIdx.y;
  const int co  = blockIdx.z;
  const float* x = co ? x1 : x0;
  __shared__ __attribute__((aligned(16))) __bf16 tile[256 * 72];
  __shared__ float redp[64];   // [wv*16 + kind*8 + g] stats1 per-wave partials
  __shared__ float reds[16];   // skip stats: [kind*8 + g]
  const int t = threadIdx.x;    // = pixel x within row
  const int wv = t >> 6, lane = t & 63;

  const float* xbase = x + (size_t)b * 64 * HW + (size_t)row * WD + t;
  __bf16* xtbase = xt + (((size_t)(co * NB + b) * HW) + (size_t)row * WD + t) * 64;

  for (int cg = 0; cg < 8; ++cg) {
    bf16x8 v;
    float sum = 0.f, sq = 0.f;
#pragma unroll
    for (int j = 0; j < 8; ++j) {
      float f = xbase[(size_t)(cg * 8 + j) * HW];
      v[j] = (__bf16)f;
      sum += f;
      sq = fmaf(f, f, sq);
    }
    *(bf16x8*)&tile[t * 72 + cg * 8] = v;
    *(bf16x8*)&xtbase[cg * 8] = v;
#pragma unroll
    for (int m = 1; m < 64; m <<= 1) {
      sum += __shfl_xor(sum, m, 64);
      sq  += __shfl_xor(sq, m, 64);
    }
    if (lane == 0) {
      redp[wv * 16 + cg] = sum;
      redp[wv * 16 + 8 + cg] = sq;
    }
  }
  __syncthreads();

  const int ln = lane & 15, q = lane >> 4;
  const int ch0 = wv * 16 + q * 4;
  bf16x8 a0, a1;
#pragma unroll
  for (int j = 0; j < 8; ++j) {
    a0[j] = (__bf16)wskip[(wv * 16 + ln) * 64 + q * 8 + j];
    a1[j] = (__bf16)wskip[(wv * 16 + ln) * 64 + 32 + q * 8 + j];
  }
  float bia[4];
#pragma unroll
  for (int r = 0; r < 4; ++r) bia[r] = bskip[ch0 + r];

  float ssum = 0.f, ssq = 0.f;
  for (int n = 0; n < 16; ++n) {
    f32x4 acc = {0.f, 0.f, 0.f, 0.f};
    bf16x8 b0 = *(const bf16x8*)&tile[(n * 16 + ln) * 72 + q * 8];
    bf16x8 b1 = *(const bf16x8*)&tile[(n * 16 + ln) * 72 + 32 + q * 8];
    acc = MFMA16(a0, b0, acc);
    acc = MFMA16(a1, b1, acc);
    bf16x4 sv;
    float v[4];
#pragma unroll
    for (int r = 0; r < 4; ++r) {
      v[r] = acc[r] + bia[r];
      ssum += v[r];
      ssq = fmaf(v[r], v[r], ssq);
      sv[r] = (__bf16)v[r];
    }
    // fragment-native: [(co*NB+b)][row*16+n][wv*4+q][ln][r] -> 8 B/lane contiguous per wave
    size_t sb = ((size_t)(co * NB + b) * 4096 + row * 16 + n) * 1024 + (wv * 4 + q) * 64 + ln * 4;
    *(bf16x4*)&sout[sb] = sv;
  }
#pragma unroll
  for (int m = 1; m < 32; m <<= 1) {
    ssum += __shfl_xor(ssum, m, 64);
    ssq  += __shfl_xor(ssq, m, 64);
  }
  if (lane == 0)  { reds[2 * wv] = ssum;     reds[8 + 2 * wv] = ssq; }
  if (lane == 32) { reds[2 * wv + 1] = ssum; reds[8 + 2 * wv + 1] = ssq; }

  __syncthreads();
  if (t < 32) {
    float val;
    if (t < 16) val = redp[t] + redp[16 + t] + redp[32 + t] + redp[48 + t];
    else val = reds[t - 16];
    const int bf1 = (co * 2 + b) * 256 + row;
    p1[(size_t)bf1 * 32 + t] = val;
  }
}

// ---------------- k_r1: reduce p1 -> nrm1 + nrmS (scale/shift per b,ch), f64 accum ----------------
__global__ __launch_bounds__(256) void k_r1(
    const float* __restrict__ p1, const float* __restrict__ g1, const float* __restrict__ be1,
    const float* __restrict__ gsk, const float* __restrict__ besk, float* __restrict__ nrm) {
  const int t = threadIdx.x;
  __shared__ double red[64];
  const int sid = t >> 2, sub = t & 3;           // sid = which*32 + b*16 + kind*8 + g
  const int which = sid >> 5, b = (sid >> 4) & 1, kg = sid & 15;
  const int col = which * 16 + kg;
  double v = 0.0;
  for (int j = sub; j < 512; j += 4) {
    int co = j >> 8, rr = j & 255;
    v += (double)p1[((size_t)(co * 2 + b) * 256 + rr) * 32 + col];
  }
  v += __shfl_xor(v, 1, 64);
  v += __shfl_xor(v, 2, 64);
  if (sub == 0) red[sid] = v;
  __syncthreads();
  {
    int half = t >> 7;           // 0: nrm1, 1: nrmS
    int b2 = (t >> 6) & 1, ch = t & 63, g = ch >> 3;
    int base = half * 32 + b2 * 16;
    double mean = red[base + g] * INV_N;
    double var  = red[base + 8 + g] * INV_N - mean * mean;
    float inv  = rsqrtf((float)var + EPSV);
    float ga = half ? gsk[ch] : g1[ch];
    float be = half ? besk[ch] : be1[ch];   // skip GN beta = beta_skip (NOT bias_skip)
    float sc = inv * ga;
    nrm[half * 256 + b2 * 128 + ch] = sc;
    nrm[half * 256 + b2 * 128 + 64 + ch] = be - (float)mean * sc;
  }
}

// ---------------- k2: norm1+relu staging, qc_conv1 GEMM, stats2 partials ----------------
__global__ __launch_bounds__(256) void k2(
    const __bf16* __restrict__ xt, const __bf16* __restrict__ A1,
    const float* __restrict__ nrm, const float* __restrict__ bias1,
    __bf16* __restrict__ h, float* __restrict__ p2) {
  // XCD swizzle: band of 64 consecutive tiles (4 tile-rows) per XCD for halo L2 locality
  const int blk = ((blockIdx.x & 7) << 6) | (blockIdx.x >> 3);
  const int tx = blk & 15, ty = blk >> 4;  // 16 x 32 tiles of 16x8
  const int b = blockIdx.y;
  const int y0p = ty * 8, x0p = tx * 16;
  __shared__ __attribute__((aligned(16))) __bf16 tl[2][153 * 72];  // 9x17 ext tiles
  __shared__ float sc[64], sh[64];
  __shared__ float lst[16];
  const int t = threadIdx.x;

  if (t < 64) {
    sc[t] = nrm[b * 128 + t];
    sh[t] = nrm[b * 128 + 64 + t];
  }
  if (t < 16) lst[t] = 0.f;
  __syncthreads();

  for (int u = t; u < 2 * 153 * 8; u += 256) {
    int cs = u / 1224;
    int rr = u - cs * 1224;
    int px = rr >> 3, cg = rr & 7;
    int ly = px / 17, lx = px - ly * 17;
    int gy = y0p + ly - cs, gx = x0p + lx - cs;
    bf16x8 v;
#pragma unroll
    for (int j = 0; j < 8; ++j) v[j] = (__bf16)0.f;
    if ((unsigned)gy < 256u && (unsigned)gx < 256u) {
      bf16x8 raw = *(const bf16x8*)&xt[(((size_t)(cs * NB + b) * WD + gy) * WD + gx) * 64 + cg * 8];
#pragma unroll
      for (int j = 0; j < 8; ++j) {
        float f = fmaf((float)raw[j], sc[cg * 8 + j], sh[cg * 8 + j]);
        v[j] = (__bf16)fmaxf(f, 0.f);
      }
    }
    *(bf16x8*)&tl[cs][px * 72 + cg * 8] = v;
  }
  __syncthreads();

  const int wv = t >> 6, lane = t & 63, ln = lane & 15, q = lane >> 4;
  const int co = wv & 1, mh = wv >> 1;
  const int q8 = q * 8;
  bf16x8 af[2][10];
#pragma unroll
  for (int m = 0; m < 2; ++m)
#pragma unroll
    for (int kk = 0; kk < 10; ++kk)
      af[m][kk] = *(const bf16x8*)&A1[(mh * 32 + m * 16 + ln) * 320 + kk * 32 + q8];

  f32x4 acc[8][2];
#pragma unroll
  for (int n = 0; n < 8; ++n)
#pragma unroll
    for (int m = 0; m < 2; ++m) acc[n][m] = (f32x4){0.f, 0.f, 0.f, 0.f};

  const __bf16* tc = tl[co];
  const __bf16* to = tl[1 - co];
#pragma unroll
  for (int n = 0; n < 8; ++n) {
    const int cpix = co ? ((n + 1) * 17 + ln + 1) : (n * 17 + ln);
    const int tb = n * 17 + ln;
    const __bf16* pc = tc + cpix * 72 + q8;
    const __bf16* p0 = to + tb * 72 + q8;
    const __bf16* p1p = to + (tb + 1) * 72 + q8;
    const __bf16* p2p = to + (tb + 17) * 72 + q8;
    const __bf16* p3 = to + (tb + 18) * 72 + q8;
    bf16x8 bb;
    bb = *(const bf16x8*)pc;         acc[n][0]=MFMA16(af[0][0],bb,acc[n][0]); acc[n][1]=MFMA16(af[1][0],bb,acc[n][1]);
    bb = *(const bf16x8*)(pc + 32);  acc[n][0]=MFMA16(af[0][1],bb,acc[n][0]); acc[n][1]=MFMA16(af[1][1],bb,acc[n][1]);
    bb = *(const bf16x8*)p0;         acc[n][0]=MFMA16(af[0][2],bb,acc[n][0]); acc[n][1]=MFMA16(af[1][2],bb,acc[n][1]);
    bb = *(const bf16x8*)(p0 + 32);  acc[n][0]=MFMA16(af[0][3],bb,acc[n][0]); acc[n][1]=MFMA16(af[1][3],bb,acc[n][1]);
    bb = *(const bf16x8*)p1p;        acc[n][0]=MFMA16(af[0][4],bb,acc[n][0]); acc[n][1]=MFMA16(af[1][4],bb,acc[n][1]);
    bb = *(const bf16x8*)(p1p + 32); acc[n][0]=MFMA16(af[0][5],bb,acc[n][0]); acc[n][1]=MFMA16(af[1][5],bb,acc[n][1]);
    bb = *(const bf16x8*)p2p;        acc[n][0]=MFMA16(af[0][6],bb,acc[n][0]); acc[n][1]=MFMA16(af[1][6],bb,acc[n][1]);
    bb = *(const bf16x8*)(p2p + 32); acc[n][0]=MFMA16(af[0][7],bb,acc[n][0]); acc[n][1]=MFMA16(af[1][7],bb,acc[n][1]);
    bb = *(const bf16x8*)p3;         acc[n][0]=MFMA16(af[0][8],bb,acc[n][0]); acc[n][1]=MFMA16(af[1][8],bb,acc[n][1]);
    bb = *(const bf16x8*)(p3 + 32);  acc[n][0]=MFMA16(af[0][9],bb,acc[n][0]); acc[n][1]=MFMA16(af[1][9],bb,acc[n][1]);
  }

  __syncthreads();   // all waves done reading tl — safe to overwrite with h values

  float s2s[2] = {0.f, 0.f}, s2q[2] = {0.f, 0.f};
  float bia[2][4];
#pragma unroll
  for (int m = 0; m < 2; ++m)
#pragma unroll
    for (int r = 0; r < 4; ++r) bia[m][r] = bias1[mh * 32 + m * 16 + q * 4 + r];

#pragma unroll
  for (int n = 0; n < 8; ++n)
#pragma unroll
    for (int m = 0; m < 2; ++m) {
      bf16x4 hv;
#pragma unroll
      for (int r = 0; r < 4; ++r) {
        float v = acc[n][m][r] + bia[m][r];
        s2s[m] += v;
        s2q[m] = fmaf(v, v, s2q[m]);
        hv[r] = (__bf16)v;
      }
      *(bf16x4*)&tl[co][(n * 16 + ln) * 72 + mh * 32 + m * 16 + q * 4] = hv;
    }

#pragma unroll
  for (int m = 0; m < 2; ++m) {
    float a_ = s2s[m], c_ = s2q[m];
#pragma unroll
    for (int mk = 1; mk < 32; mk <<= 1) {
      a_ += __shfl_xor(a_, mk, 64);
      c_ += __shfl_xor(c_, mk, 64);
    }
    if ((lane & 31) == 0) {
      int g = mh * 4 + m * 2 + (q >> 1);
      atomicAdd(&lst[g], a_);
      atomicAdd(&lst[8 + g], c_);
    }
  }
  __syncthreads();

  // coalesced h store (NHWC), 16 B/lane
  for (int i = 0; i < 8; ++i) {
    int co2 = i >> 2;
    int idx = (i & 3) * 256 + t;
    int px = idx >> 3, chunk = idx & 7;   // px 0..127
    int gy = y0p + (px >> 4), gx = x0p + (px & 15);
    bf16x8 vv = *(const bf16x8*)&tl[co2][px * 72 + chunk * 8];
    *(bf16x8*)&h[(((size_t)(co2 * NB + b) * WD + gy) * WD + gx) * 64 + chunk * 8] = vv;
  }

  if (t < 16) p2[((size_t)b * 512 + blockIdx.x) * 16 + t] = lst[t];
}

// ---------------- k_r2: reduce p2 -> nrm2, f64 accum ----------------
__global__ __launch_bounds__(256) void k_r2(
    const float* __restrict__ p2, const float* __restrict__ g2, const float* __restrict__ be2,
    float* __restrict__ nrm) {
  const int t = threadIdx.x;
  __shared__ double red[32];
  const int sid = t >> 3, sub = t & 7;   // sid = b*16 + kind*8 + g
  const int b = sid >> 4, col = sid & 15;
  double v = 0.0;
  for (int j = sub; j < 512; j += 8)
    v += (double)p2[((size_t)b * 512 + j) * 16 + col];
  v += __shfl_xor(v, 1, 64);
  v += __shfl_xor(v, 2, 64);
  v += __shfl_xor(v, 4, 64);
  if (sub == 0) red[sid] = v;
  __syncthreads();
  if (t < 128) {
    int b2 = t >> 6, ch = t & 63, g = ch >> 3;
    double mean = red[b2 * 16 + g] * INV_N;
    double var  = red[b2 * 16 + 8 + g] * INV_N - mean * mean;
    float inv  = rsqrtf((float)var + EPSV);
    float sc = inv * g2[ch];
    nrm[512 + b2 * 128 + ch] = sc;
    nrm[512 + b2 * 128 + 64 + ch] = be2[ch] - (float)mean * sc;
  }
}

// ---------------- k3: norm2+relu staging, qc_conv2 GEMM, + skip-norm + fp32 out ----------------
__global__ __launch_bounds__(256) void k3(
    const __bf16* __restrict__ hin, const __bf16* __restrict__ A2,
    const float* __restrict__ nrm, const float* __restrict__ bias2,
    const __bf16* __restrict__ sin_, float* __restrict__ out) {
  const int blk = ((blockIdx.x & 7) << 6) | (blockIdx.x >> 3);
  const int tx = blk & 15, ty = blk >> 4;
  const int b = blockIdx.y;
  const int y0p = ty * 8, x0p = tx * 16;
  __shared__ __attribute__((aligned(16))) __bf16 tl[2][153 * 72];
  __shared__ float sc2[64], sh2[64], scS[64], shS[64];
  const int t = threadIdx.x;

  if (t < 64) {
    sc2[t] = nrm[512 + b * 128 + t];
    sh2[t] = nrm[512 + b * 128 + 64 + t];
    scS[t] = nrm[256 + b * 128 + t];
    shS[t] = nrm[256 + b * 128 + 64 + t];
  }
  __syncthreads();

  for (int u = t; u < 2 * 153 * 8; u += 256) {
    int cs = u / 1224;
    int rr = u - cs * 1224;
    int px = rr >> 3, cg = rr & 7;
    int ly = px / 17, lx = px - ly * 17;
    int gy = y0p + ly - cs, gx = x0p + lx - cs;
    bf16x8 v;
#pragma unroll
    for (int j = 0; j < 8; ++j) v[j] = (__bf16)0.f;
    if ((unsigned)gy < 256u && (unsigned)gx < 256u) {
      bf16x8 raw = *(const bf16x8*)&hin[(((size_t)(cs * NB + b) * WD + gy) * WD + gx) * 64 + cg * 8];
#pragma unroll
      for (int j = 0; j < 8; ++j) {
        float f = fmaf((float)raw[j], sc2[cg * 8 + j], sh2[cg * 8 + j]);
        v[j] = (__bf16)fmaxf(f, 0.f);
      }
    }
    *(bf16x8*)&tl[cs][px * 72 + cg * 8] = v;
  }
  __syncthreads();

  const int wv = t >> 6, lane = t & 63, ln = lane & 15, q = lane >> 4;
  const int co = wv & 1, mh = wv >> 1;
  const int q8 = q * 8;
  bf16x8 af[2][10];
#pragma unroll
  for (int m = 0; m < 2; ++m)
#pragma unroll
    for (int kk = 0; kk < 10; ++kk)
      af[m][kk] = *(const bf16x8*)&A2[(mh * 32 + m * 16 + ln) * 320 + kk * 32 + q8];

  f32x4 acc[8][2];
#pragma unroll
  for (int n = 0; n < 8; ++n)
#pragma unroll
    for (int m = 0; m < 2; ++m) acc[n][m] = (f32x4){0.f, 0.f, 0.f, 0.f};

  const __bf16* tc = tl[co];
  const __bf16* to = tl[1 - co];
#pragma unroll
  for (int n = 0; n < 8; ++n) {
    const int cpix = co ? ((n + 1) * 17 + ln + 1) : (n * 17 + ln);
    const int tb = n * 17 + ln;
    const __bf16* pc = tc + cpix * 72 + q8;
    const __bf16* p0 = to + tb * 72 + q8;
    const __bf16* p1p = to + (tb + 1) * 72 + q8;
    const __bf16* p2p = to + (tb + 17) * 72 + q8;
    const __bf16* p3 = to + (tb + 18) * 72 + q8;
    bf16x8 bb;
    bb = *(const bf16x8*)pc;         acc[n][0]=MFMA16(af[0][0],bb,acc[n][0]); acc[n][1]=MFMA16(af[1][0],bb,acc[n][1]);
    bb = *(const bf16x8*)(pc + 32);  acc[n][0]=MFMA16(af[0][1],bb,acc[n][0]); acc[n][1]=MFMA16(af[1][1],bb,acc[n][1]);
    bb = *(const bf16x8*)p0;         acc[n][0]=MFMA16(af[0][2],bb,acc[n][0]); acc[n][1]=MFMA16(af[1][2],bb,acc[n][1]);
    bb = *(const bf16x8*)(p0 + 32);  acc[n][0]=MFMA16(af[0][3],bb,acc[n][0]); acc[n][1]=MFMA16(af[1][3],bb,acc[n][1]);
    bb = *(const bf16x8*)p1p;        acc[n][0]=MFMA16(af[0][4],bb,acc[n][0]); acc[n][1]=MFMA16(af[1][4],bb,acc[n][1]);
    bb = *(const bf16x8*)(p1p + 32); acc[n][0]=MFMA16(af[0][5],bb,acc[n][0]); acc[n][1]=MFMA16(af[1][5],bb,acc[n][1]);
    bb = *(const bf16x8*)p2p;        acc[n][0]=MFMA16(af[0][6],bb,acc[n][0]); acc[n][1]=MFMA16(af[1][6],bb,acc[n][1]);
    bb = *(const bf16x8*)(p2p + 32); acc[n][0]=MFMA16(af[0][7],bb,acc[n][0]); acc[n][1]=MFMA16(af[1][7],bb,acc[n][1]);
    bb = *(const bf16x8*)p3;         acc[n][0]=MFMA16(af[0][8],bb,acc[n][0]); acc[n][1]=MFMA16(af[1][8],bb,acc[n][1]);
    bb = *(const bf16x8*)(p3 + 32);  acc[n][0]=MFMA16(af[0][9],bb,acc[n][0]); acc[n][1]=MFMA16(af[1][9],bb,acc[n][1]);
  }

  float bia[2][4], sA[2][4], sB[2][4];
#pragma unroll
  for (int m = 0; m < 2; ++m)
#pragma unroll
    for (int r = 0; r < 4; ++r) {
      int ch = mh * 32 + m * 16 + q * 4 + r;
      bia[m][r] = bias2[ch];
      sA[m][r] = scS[ch];
      sB[m][r] = shS[ch];
    }

#pragma unroll
  for (int n = 0; n < 8; ++n) {
    int gy = y0p + n;
#pragma unroll
    for (int m = 0; m < 2; ++m) {
      int ch0 = mh * 32 + m * 16 + q * 4;
      // fragment-native s read: matches k1's store bijection
      size_t sb = ((size_t)(co * NB + b) * 4096 + gy * 16 + tx) * 1024 + (mh * 8 + m * 4 + q) * 64 + ln * 4;
      bf16x4 sv = *(const bf16x4*)&sin_[sb];
      size_t ob = ((size_t)(co * NB + b) * 64 + ch0) * HW + (size_t)gy * WD + x0p + ln;
#pragma unroll
      for (int r = 0; r < 4; ++r) {
        float v = acc[n][m][r] + bia[m][r] + fmaf((float)sv[r], sA[m][r], sB[m][r]);
        out[ob + (size_t)r * HW] = v;
      }
    }
  }
}

extern "C" void kernel_launch(void* const* d_in, const int* in_sizes, int n_in,
                              void* d_out, int out_size, void* d_ws, size_t ws_size,
                              hipStream_t stream) {
  (void)in_sizes; (void)n_in; (void)out_size; (void)ws_size;
  const float* x0    = (const float*)d_in[0];
  const float* x1    = (const float*)d_in[1];
  const float* g1    = (const float*)d_in[2];
  const float* b1    = (const float*)d_in[3];
  const float* w1c   = (const float*)d_in[4];
  const float* w1k   = (const float*)d_in[5];
  const float* bias1 = (const float*)d_in[6];
  const float* g2    = (const float*)d_in[7];
  const float* b2    = (const float*)d_in[8];
  const float* w2c   = (const float*)d_in[9];
  const float* w2k   = (const float*)d_in[10];
  const float* bias2 = (const float*)d_in[11];
  const float* wsk   = (const float*)d_in[12];
  const float* bsk   = (const float*)d_in[13];
  const float* gsk   = (const float*)d_in[14];
  const float* besk  = (const float*)d_in[15];

  char* ws = (char*)d_ws;
  float*  p1 = (float*)(ws + OFF_P1);
  float*  p2 = (float*)(ws + OFF_P2);
  float*  nrm = (float*)(ws + OFF_NRM);
  __bf16* A1 = (__bf16*)(ws + OFF_A1);
  __bf16* A2 = (__bf16*)(ws + OFF_A2);
  __bf16* xt = (__bf16*)(ws + OFF_XT);
  __bf16* s  = (__bf16*)(ws + OFF_S);
  __bf16* h  = (__bf16*)(ws + OFF_H);

  k_prep<<<2, 256, 0, stream>>>(w1c, w1k, w2c, w2k, A1, A2);
  k1<<<dim3(256, 2, 2), 256, 0, stream>>>(x0, x1, wsk, bsk, xt, s, p1);
  k_r1<<<1, 256, 0, stream>>>(p1, g1, b1, gsk, besk, nrm);
  k2<<<dim3(512, 2), 256, 0, stream>>>(xt, A1, nrm, bias1, h, p2);
  k_r2<<<1, 256, 0, stream>>>(p2, g2, b2, nrm);
  k3<<<dim3(512, 2), 256, 0, stream>>>(h, A2, nrm, bias2, s, (float*)d_out);
}

// Round 7
// 309.133 us; speedup vs baseline: 2.2445x; 1.0617x over previous
//
#include <hip/hip_runtime.h>

typedef __attribute__((ext_vector_type(8))) __bf16 bf16x8;
typedef __attribute__((ext_vector_type(4))) __bf16 bf16x4;
typedef __attribute__((ext_vector_type(4))) float f32x4;

#define MFMA16(a,b,c) __builtin_amdgcn_mfma_f32_16x16x32_bf16(a,b,c,0,0,0)

static constexpr int HW = 65536;   // 256*256
static constexpr int WD = 256;
static constexpr int NB = 2;       // batch
static constexpr double INV_N = 1.0 / 1048576.0;   // 8ch*65536px*2cosets
static constexpr float EPSV = 1e-5f;

// workspace layout (bytes)
static constexpr size_t OFF_P1  = 0;                   // 1024 blocks x 32 f32 partials (stats1+skip)
static constexpr size_t OFF_P2  = 131072;              // 1024 blocks x 16 f32 partials (stats2)
static constexpr size_t OFF_NRM = 196608;              // 768 f32: nrm1[2][2][64], nrmS(+256), nrm2(+512)
static constexpr size_t OFF_A1  = 200704;              // 20480 bf16
static constexpr size_t OFF_A2  = OFF_A1 + 40960;
static constexpr size_t OFF_XT  = OFF_A2 + 40960;
static constexpr size_t SZ_T    = (size_t)2 * NB * HW * 64 * 2;  // 32 MiB
static constexpr size_t OFF_S   = OFF_XT + SZ_T;
static constexpr size_t OFF_H   = OFF_S + SZ_T;

// ---------------- weight prep: A[o][k], k: [0,64)=center, [64+t*64+c]=tap t ----------------
__global__ void k_prep(const float* __restrict__ wc1, const float* __restrict__ wk1,
                       const float* __restrict__ wc2, const float* __restrict__ wk2,
                       __bf16* __restrict__ A1, __bf16* __restrict__ A2) {
  const int stage = blockIdx.x;
  const float* wc = stage ? wc2 : wc1;
  const float* wk = stage ? wk2 : wk1;
  __bf16* A = stage ? A2 : A1;
  for (int idx = threadIdx.x; idx < 64 * 320; idx += blockDim.x) {
    int o = idx / 320, k = idx - o * 320;
    float v;
    if (k < 64) v = wc[o * 64 + k];
    else {
      int t = (k - 64) >> 6;
      int c = k & 63;
      v = wk[(o * 64 + c) * 4 + t];
    }
    A[idx] = (__bf16)v;
  }
}

// ---------------- k1: stats1 partials + skip GEMM + NHWC bf16 transpose ----------------
// s layout (fragment-native): [(co*NB+b)][pxhi=px/16][ch/4][px&15][ch&3], bf16
__global__ __launch_bounds__(256) void k1(
    const float* __restrict__ x0, const float* __restrict__ x1,
    const float* __restrict__ wskip, const float* __restrict__ bskip,
    __bf16* __restrict__ xt, __bf16* __restrict__ sout, float* __restrict__ p1) {
  const int row = blockIdx.x;   // 0..255 (H row)
  const int b   = blockIdx.y;
  const int co  = blockIdx.z;
  const float* x = co ? x1 : x0;
  __shared__ __attribute__((aligned(16))) __bf16 tile[256 * 72];
  __shared__ float redp[256];   // [(wv*4+q)*16 + kind*8 + g] 16-lane stats1 partials
  __shared__ float reds[32];    // skip stats 16-lane partials: [kind*16 + wv*4 + q]
  const int t = threadIdx.x;    // = pixel x within row
  const int wv = t >> 6, lane = t & 63;

  const float* xbase = x + (size_t)b * 64 * HW + (size_t)row * WD + t;
  __bf16* xtbase = xt + (((size_t)(co * NB + b) * HW) + (size_t)row * WD + t) * 64;

  // phase A: batched loads, thread-local stats (no shuffles inside the loop)
  float gsum[8], gsq[8];
#pragma unroll
  for (int g = 0; g < 8; ++g) { gsum[g] = 0.f; gsq[g] = 0.f; }
#pragma unroll
  for (int cg = 0; cg < 8; ++cg) {
    float f[8];
#pragma unroll
    for (int j = 0; j < 8; ++j) f[j] = xbase[(size_t)(cg * 8 + j) * HW];
    bf16x8 v;
#pragma unroll
    for (int j = 0; j < 8; ++j) {
      v[j] = (__bf16)f[j];
      gsum[cg] += f[j];
      gsq[cg] = fmaf(f[j], f[j], gsq[cg]);
    }
    *(bf16x8*)&tile[t * 72 + cg * 8] = v;
    *(bf16x8*)&xtbase[cg * 8] = v;
  }
  // one 4-step shuffle round: 16 independent chains -> 16-lane partials
#pragma unroll
  for (int g = 0; g < 8; ++g) {
#pragma unroll
    for (int m = 1; m < 16; m <<= 1) {
      gsum[g] += __shfl_xor(gsum[g], m, 64);
      gsq[g]  += __shfl_xor(gsq[g], m, 64);
    }
  }
  {
    const int q0 = lane >> 4;
    if ((lane & 15) == 0) {
#pragma unroll
      for (int g = 0; g < 8; ++g) {
        redp[(wv * 4 + q0) * 16 + g] = gsum[g];
        redp[(wv * 4 + q0) * 16 + 8 + g] = gsq[g];
      }
    }
  }
  __syncthreads();

  // phase B: skip GEMM (MFMA), s stored fragment-native
  const int ln = lane & 15, q = lane >> 4;
  const int ch0 = wv * 16 + q * 4;
  bf16x8 a0, a1;
#pragma unroll
  for (int j = 0; j < 8; ++j) {
    a0[j] = (__bf16)wskip[(wv * 16 + ln) * 64 + q * 8 + j];
    a1[j] = (__bf16)wskip[(wv * 16 + ln) * 64 + 32 + q * 8 + j];
  }
  float bia[4];
#pragma unroll
  for (int r = 0; r < 4; ++r) bia[r] = bskip[ch0 + r];

  float ssum = 0.f, ssq = 0.f;
  for (int n = 0; n < 16; ++n) {
    f32x4 acc = {0.f, 0.f, 0.f, 0.f};
    bf16x8 b0 = *(const bf16x8*)&tile[(n * 16 + ln) * 72 + q * 8];
    bf16x8 b1 = *(const bf16x8*)&tile[(n * 16 + ln) * 72 + 32 + q * 8];
    acc = MFMA16(a0, b0, acc);
    acc = MFMA16(a1, b1, acc);
    bf16x4 sv;
    float v[4];
#pragma unroll
    for (int r = 0; r < 4; ++r) {
      v[r] = acc[r] + bia[r];
      ssum += v[r];
      ssq = fmaf(v[r], v[r], ssq);
      sv[r] = (__bf16)v[r];
    }
    size_t sb = ((size_t)(co * NB + b) * 4096 + row * 16 + n) * 1024 + (wv * 4 + q) * 64 + ln * 4;
    *(bf16x4*)&sout[sb] = sv;
  }
#pragma unroll
  for (int m = 1; m < 16; m <<= 1) {
    ssum += __shfl_xor(ssum, m, 64);
    ssq  += __shfl_xor(ssq, m, 64);
  }
  if ((lane & 15) == 0) {
    reds[wv * 4 + q] = ssum;        // quarter q belongs to group 2*wv + (q>>1)
    reds[16 + wv * 4 + q] = ssq;
  }

  __syncthreads();
  if (t < 32) {
    float val;
    if (t < 16) {
      val = 0.f;
#pragma unroll
      for (int k = 0; k < 16; ++k) val += redp[k * 16 + t];
    } else {
      int kind = (t >> 3) & 1, g = t & 7;   // t in [16,24): skip sums; [24,32): skip sqs
      int wvv = g >> 1, qp = g & 1;
      val = reds[kind * 16 + wvv * 4 + qp * 2] + reds[kind * 16 + wvv * 4 + qp * 2 + 1];
    }
    const int bf1 = (co * 2 + b) * 256 + row;
    p1[(size_t)bf1 * 32 + t] = val;
  }
}

// ---------------- k_r1: reduce p1 -> nrm1 + nrmS (scale/shift per b,ch), f64 accum ----------------
__global__ __launch_bounds__(256) void k_r1(
    const float* __restrict__ p1, const float* __restrict__ g1, const float* __restrict__ be1,
    const float* __restrict__ gsk, const float* __restrict__ besk, float* __restrict__ nrm) {
  const int t = threadIdx.x;
  __shared__ double red[64];
  const int sid = t >> 2, sub = t & 3;           // sid = which*32 + b*16 + kind*8 + g
  const int which = sid >> 5, b = (sid >> 4) & 1, kg = sid & 15;
  const int col = which * 16 + kg;
  double v = 0.0;
  for (int j = sub; j < 512; j += 4) {
    int co = j >> 8, rr = j & 255;
    v += (double)p1[((size_t)(co * 2 + b) * 256 + rr) * 32 + col];
  }
  v += __shfl_xor(v, 1, 64);
  v += __shfl_xor(v, 2, 64);
  if (sub == 0) red[sid] = v;
  __syncthreads();
  {
    int half = t >> 7;           // 0: nrm1, 1: nrmS
    int b2 = (t >> 6) & 1, ch = t & 63, g = ch >> 3;
    int base = half * 32 + b2 * 16;
    double mean = red[base + g] * INV_N;
    double var  = red[base + 8 + g] * INV_N - mean * mean;
    float inv  = rsqrtf((float)var + EPSV);
    float ga = half ? gsk[ch] : g1[ch];
    float be = half ? besk[ch] : be1[ch];   // skip GN beta = beta_skip (NOT bias_skip)
    float sc = inv * ga;
    nrm[half * 256 + b2 * 128 + ch] = sc;
    nrm[half * 256 + b2 * 128 + 64 + ch] = be - (float)mean * sc;
  }
}

// ---------------- k2: norm1+relu staging, qc_conv1 GEMM, stats2 partials ----------------
__global__ __launch_bounds__(256) void k2(
    const __bf16* __restrict__ xt, const __bf16* __restrict__ A1,
    const float* __restrict__ nrm, const float* __restrict__ bias1,
    __bf16* __restrict__ h, float* __restrict__ p2) {
  // XCD swizzle: band of 64 consecutive tiles (4 tile-rows) per XCD for halo L2 locality
  const int blk = ((blockIdx.x & 7) << 6) | (blockIdx.x >> 3);
  const int tx = blk & 15, ty = blk >> 4;  // 16 x 32 tiles of 16x8
  const int b = blockIdx.y;
  const int y0p = ty * 8, x0p = tx * 16;
  __shared__ __attribute__((aligned(16))) __bf16 tl[2][153 * 72];  // 9x17 ext tiles
  __shared__ float sc[64], sh[64];
  __shared__ float lst[16];
  const int t = threadIdx.x;

  if (t < 64) {
    sc[t] = nrm[b * 128 + t];
    sh[t] = nrm[b * 128 + 64 + t];
  }
  if (t < 16) lst[t] = 0.f;
  __syncthreads();

  // staging: fixed 10 predicated iterations, fully unrolled (loads batched)
#pragma unroll
  for (int i = 0; i < 10; ++i) {
    int u = t + i * 256;
    if (u < 2 * 153 * 8) {
      int cs = u / 1224;
      int rr = u - cs * 1224;
      int px = rr >> 3, cg = rr & 7;
      int ly = px / 17, lx = px - ly * 17;
      int gy = y0p + ly - cs, gx = x0p + lx - cs;
      bf16x8 v;
#pragma unroll
      for (int j = 0; j < 8; ++j) v[j] = (__bf16)0.f;
      if ((unsigned)gy < 256u && (unsigned)gx < 256u) {
        bf16x8 raw = *(const bf16x8*)&xt[(((size_t)(cs * NB + b) * WD + gy) * WD + gx) * 64 + cg * 8];
#pragma unroll
        for (int j = 0; j < 8; ++j) {
          float f = fmaf((float)raw[j], sc[cg * 8 + j], sh[cg * 8 + j]);
          v[j] = (__bf16)fmaxf(f, 0.f);
        }
      }
      *(bf16x8*)&tl[cs][px * 72 + cg * 8] = v;
    }
  }
  __syncthreads();

  const int wv = t >> 6, lane = t & 63, ln = lane & 15, q = lane >> 4;
  const int co = wv & 1, mh = wv >> 1;
  const int q8 = q * 8;
  bf16x8 af[2][10];
#pragma unroll
  for (int m = 0; m < 2; ++m)
#pragma unroll
    for (int kk = 0; kk < 10; ++kk)
      af[m][kk] = *(const bf16x8*)&A1[(mh * 32 + m * 16 + ln) * 320 + kk * 32 + q8];

  f32x4 acc[8][2];
#pragma unroll
  for (int n = 0; n < 8; ++n)
#pragma unroll
    for (int m = 0; m < 2; ++m) acc[n][m] = (f32x4){0.f, 0.f, 0.f, 0.f};

  const __bf16* tc = tl[co];
  const __bf16* to = tl[1 - co];
#pragma unroll
  for (int n = 0; n < 8; ++n) {
    const int cpix = co ? ((n + 1) * 17 + ln + 1) : (n * 17 + ln);
    const int tb = n * 17 + ln;
    const __bf16* pc = tc + cpix * 72 + q8;
    const __bf16* p0 = to + tb * 72 + q8;
    const __bf16* p1p = to + (tb + 1) * 72 + q8;
    const __bf16* p2p = to + (tb + 17) * 72 + q8;
    const __bf16* p3 = to + (tb + 18) * 72 + q8;
    bf16x8 bb;
    bb = *(const bf16x8*)pc;         acc[n][0]=MFMA16(af[0][0],bb,acc[n][0]); acc[n][1]=MFMA16(af[1][0],bb,acc[n][1]);
    bb = *(const bf16x8*)(pc + 32);  acc[n][0]=MFMA16(af[0][1],bb,acc[n][0]); acc[n][1]=MFMA16(af[1][1],bb,acc[n][1]);
    bb = *(const bf16x8*)p0;         acc[n][0]=MFMA16(af[0][2],bb,acc[n][0]); acc[n][1]=MFMA16(af[1][2],bb,acc[n][1]);
    bb = *(const bf16x8*)(p0 + 32);  acc[n][0]=MFMA16(af[0][3],bb,acc[n][0]); acc[n][1]=MFMA16(af[1][3],bb,acc[n][1]);
    bb = *(const bf16x8*)p1p;        acc[n][0]=MFMA16(af[0][4],bb,acc[n][0]); acc[n][1]=MFMA16(af[1][4],bb,acc[n][1]);
    bb = *(const bf16x8*)(p1p + 32); acc[n][0]=MFMA16(af[0][5],bb,acc[n][0]); acc[n][1]=MFMA16(af[1][5],bb,acc[n][1]);
    bb = *(const bf16x8*)p2p;        acc[n][0]=MFMA16(af[0][6],bb,acc[n][0]); acc[n][1]=MFMA16(af[1][6],bb,acc[n][1]);
    bb = *(const bf16x8*)(p2p + 32); acc[n][0]=MFMA16(af[0][7],bb,acc[n][0]); acc[n][1]=MFMA16(af[1][7],bb,acc[n][1]);
    bb = *(const bf16x8*)p3;         acc[n][0]=MFMA16(af[0][8],bb,acc[n][0]); acc[n][1]=MFMA16(af[1][8],bb,acc[n][1]);
    bb = *(const bf16x8*)(p3 + 32);  acc[n][0]=MFMA16(af[0][9],bb,acc[n][0]); acc[n][1]=MFMA16(af[1][9],bb,acc[n][1]);
  }

  __syncthreads();   // all waves done reading tl — safe to overwrite with h values

  float s2s[2] = {0.f, 0.f}, s2q[2] = {0.f, 0.f};
  float bia[2][4];
#pragma unroll
  for (int m = 0; m < 2; ++m)
#pragma unroll
    for (int r = 0; r < 4; ++r) bia[m][r] = bias1[mh * 32 + m * 16 + q * 4 + r];

#pragma unroll
  for (int n = 0; n < 8; ++n)
#pragma unroll
    for (int m = 0; m < 2; ++m) {
      bf16x4 hv;
#pragma unroll
      for (int r = 0; r < 4; ++r) {
        float v = acc[n][m][r] + bia[m][r];
        s2s[m] += v;
        s2q[m] = fmaf(v, v, s2q[m]);
        hv[r] = (__bf16)v;
      }
      *(bf16x4*)&tl[co][(n * 16 + ln) * 72 + mh * 32 + m * 16 + q * 4] = hv;
    }

#pragma unroll
  for (int m = 0; m < 2; ++m) {
    float a_ = s2s[m], c_ = s2q[m];
#pragma unroll
    for (int mk = 1; mk < 32; mk <<= 1) {
      a_ += __shfl_xor(a_, mk, 64);
      c_ += __shfl_xor(c_, mk, 64);
    }
    if ((lane & 31) == 0) {
      int g = mh * 4 + m * 2 + (q >> 1);
      atomicAdd(&lst[g], a_);
      atomicAdd(&lst[8 + g], c_);
    }
  }
  __syncthreads();

  // coalesced h store (NHWC), 16 B/lane
#pragma unroll
  for (int i = 0; i < 8; ++i) {
    int co2 = i >> 2;
    int idx = (i & 3) * 256 + t;
    int px = idx >> 3, chunk = idx & 7;   // px 0..127
    int gy = y0p + (px >> 4), gx = x0p + (px & 15);
    bf16x8 vv = *(const bf16x8*)&tl[co2][px * 72 + chunk * 8];
    *(bf16x8*)&h[(((size_t)(co2 * NB + b) * WD + gy) * WD + gx) * 64 + chunk * 8] = vv;
  }

  if (t < 16) p2[((size_t)b * 512 + blockIdx.x) * 16 + t] = lst[t];
}

// ---------------- k_r2: reduce p2 -> nrm2, f64 accum ----------------
__global__ __launch_bounds__(256) void k_r2(
    const float* __restrict__ p2, const float* __restrict__ g2, const float* __restrict__ be2,
    float* __restrict__ nrm) {
  const int t = threadIdx.x;
  __shared__ double red[32];
  const int sid = t >> 3, sub = t & 7;   // sid = b*16 + kind*8 + g
  const int b = sid >> 4, col = sid & 15;
  double v = 0.0;
  for (int j = sub; j < 512; j += 8)
    v += (double)p2[((size_t)b * 512 + j) * 16 + col];
  v += __shfl_xor(v, 1, 64);
  v += __shfl_xor(v, 2, 64);
  v += __shfl_xor(v, 4, 64);
  if (sub == 0) red[sid] = v;
  __syncthreads();
  if (t < 128) {
    int b2 = t >> 6, ch = t & 63, g = ch >> 3;
    double mean = red[b2 * 16 + g] * INV_N;
    double var  = red[b2 * 16 + 8 + g] * INV_N - mean * mean;
    float inv  = rsqrtf((float)var + EPSV);
    float sc = inv * g2[ch];
    nrm[512 + b2 * 128 + ch] = sc;
    nrm[512 + b2 * 128 + 64 + ch] = be2[ch] - (float)mean * sc;
  }
}

// ---------------- k3: norm2+relu staging, qc_conv2 GEMM, + skip-norm + fp32 out ----------------
__global__ __launch_bounds__(256) void k3(
    const __bf16* __restrict__ hin, const __bf16* __restrict__ A2,
    const float* __restrict__ nrm, const float* __restrict__ bias2,
    const __bf16* __restrict__ sin_, float* __restrict__ out) {
  const int blk = ((blockIdx.x & 7) << 6) | (blockIdx.x >> 3);
  const int tx = blk & 15, ty = blk >> 4;
  const int b = blockIdx.y;
  const int y0p = ty * 8, x0p = tx * 16;
  __shared__ __attribute__((aligned(16))) __bf16 tl[2][153 * 72];
  __shared__ float sc2[64], sh2[64], scS[64], shS[64];
  const int t = threadIdx.x;

  if (t < 64) {
    sc2[t] = nrm[512 + b * 128 + t];
    sh2[t] = nrm[512 + b * 128 + 64 + t];
    scS[t] = nrm[256 + b * 128 + t];
    shS[t] = nrm[256 + b * 128 + 64 + t];
  }
  __syncthreads();

#pragma unroll
  for (int i = 0; i < 10; ++i) {
    int u = t + i * 256;
    if (u < 2 * 153 * 8) {
      int cs = u / 1224;
      int rr = u - cs * 1224;
      int px = rr >> 3, cg = rr & 7;
      int ly = px / 17, lx = px - ly * 17;
      int gy = y0p + ly - cs, gx = x0p + lx - cs;
      bf16x8 v;
#pragma unroll
      for (int j = 0; j < 8; ++j) v[j] = (__bf16)0.f;
      if ((unsigned)gy < 256u && (unsigned)gx < 256u) {
        bf16x8 raw = *(const bf16x8*)&hin[(((size_t)(cs * NB + b) * WD + gy) * WD + gx) * 64 + cg * 8];
#pragma unroll
        for (int j = 0; j < 8; ++j) {
          float f = fmaf((float)raw[j], sc2[cg * 8 + j], sh2[cg * 8 + j]);
          v[j] = (__bf16)fmaxf(f, 0.f);
        }
      }
      *(bf16x8*)&tl[cs][px * 72 + cg * 8] = v;
    }
  }
  __syncthreads();

  const int wv = t >> 6, lane = t & 63, ln = lane & 15, q = lane >> 4;
  const int co = wv & 1, mh = wv >> 1;
  const int q8 = q * 8;
  bf16x8 af[2][10];
#pragma unroll
  for (int m = 0; m < 2; ++m)
#pragma unroll
    for (int kk = 0; kk < 10; ++kk)
      af[m][kk] = *(const bf16x8*)&A2[(mh * 32 + m * 16 + ln) * 320 + kk * 32 + q8];

  f32x4 acc[8][2];
#pragma unroll
  for (int n = 0; n < 8; ++n)
#pragma unroll
    for (int m = 0; m < 2; ++m) acc[n][m] = (f32x4){0.f, 0.f, 0.f, 0.f};

  const __bf16* tc = tl[co];
  const __bf16* to = tl[1 - co];
#pragma unroll
  for (int n = 0; n < 8; ++n) {
    const int cpix = co ? ((n + 1) * 17 + ln + 1) : (n * 17 + ln);
    const int tb = n * 17 + ln;
    const __bf16* pc = tc + cpix * 72 + q8;
    const __bf16* p0 = to + tb * 72 + q8;
    const __bf16* p1p = to + (tb + 1) * 72 + q8;
    const __bf16* p2p = to + (tb + 17) * 72 + q8;
    const __bf16* p3 = to + (tb + 18) * 72 + q8;
    bf16x8 bb;
    bb = *(const bf16x8*)pc;         acc[n][0]=MFMA16(af[0][0],bb,acc[n][0]); acc[n][1]=MFMA16(af[1][0],bb,acc[n][1]);
    bb = *(const bf16x8*)(pc + 32);  acc[n][0]=MFMA16(af[0][1],bb,acc[n][0]); acc[n][1]=MFMA16(af[1][1],bb,acc[n][1]);
    bb = *(const bf16x8*)p0;         acc[n][0]=MFMA16(af[0][2],bb,acc[n][0]); acc[n][1]=MFMA16(af[1][2],bb,acc[n][1]);
    bb = *(const bf16x8*)(p0 + 32);  acc[n][0]=MFMA16(af[0][3],bb,acc[n][0]); acc[n][1]=MFMA16(af[1][3],bb,acc[n][1]);
    bb = *(const bf16x8*)p1p;        acc[n][0]=MFMA16(af[0][4],bb,acc[n][0]); acc[n][1]=MFMA16(af[1][4],bb,acc[n][1]);
    bb = *(const bf16x8*)(p1p + 32); acc[n][0]=MFMA16(af[0][5],bb,acc[n][0]); acc[n][1]=MFMA16(af[1][5],bb,acc[n][1]);
    bb = *(const bf16x8*)p2p;        acc[n][0]=MFMA16(af[0][6],bb,acc[n][0]); acc[n][1]=MFMA16(af[1][6],bb,acc[n][1]);
    bb = *(const bf16x8*)(p2p + 32); acc[n][0]=MFMA16(af[0][7],bb,acc[n][0]); acc[n][1]=MFMA16(af[1][7],bb,acc[n][1]);
    bb = *(const bf16x8*)p3;         acc[n][0]=MFMA16(af[0][8],bb,acc[n][0]); acc[n][1]=MFMA16(af[1][8],bb,acc[n][1]);
    bb = *(const bf16x8*)(p3 + 32);  acc[n][0]=MFMA16(af[0][9],bb,acc[n][0]); acc[n][1]=MFMA16(af[1][9],bb,acc[n][1]);
  }

  float bia[2][4], sA[2][4], sB[2][4];
#pragma unroll
  for (int m = 0; m < 2; ++m)
#pragma unroll
    for (int r = 0; r < 4; ++r) {
      int ch = mh * 32 + m * 16 + q * 4 + r;
      bia[m][r] = bias2[ch];
      sA[m][r] = scS[ch];
      sB[m][r] = shS[ch];
    }

#pragma unroll
  for (int n = 0; n < 8; ++n) {
    int gy = y0p + n;
#pragma unroll
    for (int m = 0; m < 2; ++m) {
      int ch0 = mh * 32 + m * 16 + q * 4;
      // fragment-native s read: matches k1's store bijection
      size_t sb = ((size_t)(co * NB + b) * 4096 + gy * 16 + tx) * 1024 + (mh * 8 + m * 4 + q) * 64 + ln * 4;
      bf16x4 sv = *(const bf16x4*)&sin_[sb];
      size_t ob = ((size_t)(co * NB + b) * 64 + ch0) * HW + (size_t)gy * WD + x0p + ln;
#pragma unroll
      for (int r = 0; r < 4; ++r) {
        float v = acc[n][m][r] + bia[m][r] + fmaf((float)sv[r], sA[m][r], sB[m][r]);
        out[ob + (size_t)r * HW] = v;
      }
    }
  }
}

extern "C" void kernel_launch(void* const* d_in, const int* in_sizes, int n_in,
                              void* d_out, int out_size, void* d_ws, size_t ws_size,
                              hipStream_t stream) {
  (void)in_sizes; (void)n_in; (void)out_size; (void)ws_size;
  const float* x0    = (const float*)d_in[0];
  const float* x1    = (const float*)d_in[1];
  const float* g1    = (const float*)d_in[2];
  const float* b1    = (const float*)d_in[3];
  const float* w1c   = (const float*)d_in[4];
  const float* w1k   = (const float*)d_in[5];
  const float* bias1 = (const float*)d_in[6];
  const float* g2    = (const float*)d_in[7];
  const float* b2    = (const float*)d_in[8];
  const float* w2c   = (const float*)d_in[9];
  const float* w2k   = (const float*)d_in[10];
  const float* bias2 = (const float*)d_in[11];
  const float* wsk   = (const float*)d_in[12];
  const float* bsk   = (const float*)d_in[13];
  const float* gsk   = (const float*)d_in[14];
  const float* besk  = (const float*)d_in[15];

  char* ws = (char*)d_ws;
  float*  p1 = (float*)(ws + OFF_P1);
  float*  p2 = (float*)(ws + OFF_P2);
  float*  nrm = (float*)(ws + OFF_NRM);
  __bf16* A1 = (__bf16*)(ws + OFF_A1);
  __bf16* A2 = (__bf16*)(ws + OFF_A2);
  __bf16* xt = (__bf16*)(ws + OFF_XT);
  __bf16* s  = (__bf16*)(ws + OFF_S);
  __bf16* h  = (__bf16*)(ws + OFF_H);

  k_prep<<<2, 256, 0, stream>>>(w1c, w1k, w2c, w2k, A1, A2);
  k1<<<dim3(256, 2, 2), 256, 0, stream>>>(x0, x1, wsk, bsk, xt, s, p1);
  k_r1<<<1, 256, 0, stream>>>(p1, g1, b1, gsk, besk, nrm);
  k2<<<dim3(512, 2), 256, 0, stream>>>(xt, A1, nrm, bias1, h, p2);
  k_r2<<<1, 256, 0, stream>>>(p2, g2, b2, nrm);
  k3<<<dim3(512, 2), 256, 0, stream>>>(h, A2, nrm, bias2, s, (float*)d_out);
}

// Round 8
// 297.226 us; speedup vs baseline: 2.3344x; 1.0401x over previous
//
#include <hip/hip_runtime.h>

typedef __attribute__((ext_vector_type(8))) __bf16 bf16x8;
typedef __attribute__((ext_vector_type(4))) __bf16 bf16x4;
typedef __attribute__((ext_vector_type(4))) float f32x4;

#define MFMA16(a,b,c) __builtin_amdgcn_mfma_f32_16x16x32_bf16(a,b,c,0,0,0)

static constexpr int HW = 65536;   // 256*256
static constexpr int WD = 256;
static constexpr int NB = 2;       // batch
static constexpr double INV_N = 1.0 / 1048576.0;   // 8ch*65536px*2cosets
static constexpr float EPSV = 1e-5f;

// workspace layout (bytes)
static constexpr size_t OFF_P1  = 0;                   // 1024 blocks x 32 f32 partials (stats1+skip)
static constexpr size_t OFF_P2  = 131072;              // 1024 blocks x 16 f32 partials (stats2)
static constexpr size_t OFF_A1  = 200704;              // 20480 bf16
static constexpr size_t OFF_A2  = OFF_A1 + 40960;
static constexpr size_t OFF_XT  = OFF_A2 + 40960;
static constexpr size_t SZ_T    = (size_t)2 * NB * HW * 64 * 2;  // 32 MiB
static constexpr size_t OFF_S   = OFF_XT + SZ_T;
static constexpr size_t OFF_H   = OFF_S + SZ_T;

// ================ K1: weight prep (2 blocks) + stats1 partials + skip GEMM + NHWC transpose ================
// s layout (fragment-native): [(co*NB+b)][pxhi=px/16][ch/4][px&15][ch&3], bf16
__global__ __launch_bounds__(256) void K1(
    const float* __restrict__ x0, const float* __restrict__ x1,
    const float* __restrict__ wskip, const float* __restrict__ bskip,
    const float* __restrict__ wc1, const float* __restrict__ wk1,
    const float* __restrict__ wc2, const float* __restrict__ wk2,
    __bf16* __restrict__ xt, __bf16* __restrict__ sout,
    __bf16* __restrict__ A1, __bf16* __restrict__ A2, float* __restrict__ p1) {
  const int bx = blockIdx.x;
  const int t = threadIdx.x;

  if (bx >= 1024) {            // weight-prep blocks
    const int stage = bx - 1024;
    const float* wc = stage ? wc2 : wc1;
    const float* wk = stage ? wk2 : wk1;
    __bf16* A = stage ? A2 : A1;
    for (int idx = t; idx < 64 * 320; idx += 256) {
      int o = idx / 320, k = idx - o * 320;
      float v;
      if (k < 64) v = wc[o * 64 + k];
      else {
        int tp = (k - 64) >> 6;
        int c = k & 63;
        v = wk[(o * 64 + c) * 4 + tp];
      }
      A[idx] = (__bf16)v;
    }
    return;
  }

  const int row = bx & 255;
  const int b   = (bx >> 8) & 1;
  const int co  = bx >> 9;
  const float* x = co ? x1 : x0;
  __shared__ __attribute__((aligned(16))) __bf16 tile[256 * 72];
  __shared__ float redp[256];   // [(wv*4+q)*16 + kind*8 + g] 16-lane stats1 partials
  __shared__ float reds[32];    // skip stats 16-lane partials
  const int wv = t >> 6, lane = t & 63;

  const float* xbase = x + (size_t)b * 64 * HW + (size_t)row * WD + t;
  __bf16* xtbase = xt + (((size_t)(co * NB + b) * HW) + (size_t)row * WD + t) * 64;

  // phase A: batched loads, thread-local stats
  float gsum[8], gsq[8];
#pragma unroll
  for (int g = 0; g < 8; ++g) { gsum[g] = 0.f; gsq[g] = 0.f; }
#pragma unroll
  for (int cg = 0; cg < 8; ++cg) {
    float f[8];
#pragma unroll
    for (int j = 0; j < 8; ++j) f[j] = xbase[(size_t)(cg * 8 + j) * HW];
    bf16x8 v;
#pragma unroll
    for (int j = 0; j < 8; ++j) {
      v[j] = (__bf16)f[j];
      gsum[cg] += f[j];
      gsq[cg] = fmaf(f[j], f[j], gsq[cg]);
    }
    *(bf16x8*)&tile[t * 72 + cg * 8] = v;
    *(bf16x8*)&xtbase[cg * 8] = v;
  }
#pragma unroll
  for (int g = 0; g < 8; ++g) {
#pragma unroll
    for (int m = 1; m < 16; m <<= 1) {
      gsum[g] += __shfl_xor(gsum[g], m, 64);
      gsq[g]  += __shfl_xor(gsq[g], m, 64);
    }
  }
  {
    const int q0 = lane >> 4;
    if ((lane & 15) == 0) {
#pragma unroll
      for (int g = 0; g < 8; ++g) {
        redp[(wv * 4 + q0) * 16 + g] = gsum[g];
        redp[(wv * 4 + q0) * 16 + 8 + g] = gsq[g];
      }
    }
  }
  __syncthreads();

  // phase B: skip GEMM (MFMA), s stored fragment-native
  const int ln = lane & 15, q = lane >> 4;
  const int ch0 = wv * 16 + q * 4;
  bf16x8 a0, a1;
#pragma unroll
  for (int j = 0; j < 8; ++j) {
    a0[j] = (__bf16)wskip[(wv * 16 + ln) * 64 + q * 8 + j];
    a1[j] = (__bf16)wskip[(wv * 16 + ln) * 64 + 32 + q * 8 + j];
  }
  float bia[4];
#pragma unroll
  for (int r = 0; r < 4; ++r) bia[r] = bskip[ch0 + r];

  float ssum = 0.f, ssq = 0.f;
  for (int n = 0; n < 16; ++n) {
    f32x4 acc = {0.f, 0.f, 0.f, 0.f};
    bf16x8 b0 = *(const bf16x8*)&tile[(n * 16 + ln) * 72 + q * 8];
    bf16x8 b1 = *(const bf16x8*)&tile[(n * 16 + ln) * 72 + 32 + q * 8];
    acc = MFMA16(a0, b0, acc);
    acc = MFMA16(a1, b1, acc);
    bf16x4 sv;
    float v[4];
#pragma unroll
    for (int r = 0; r < 4; ++r) {
      v[r] = acc[r] + bia[r];
      ssum += v[r];
      ssq = fmaf(v[r], v[r], ssq);
      sv[r] = (__bf16)v[r];
    }
    size_t sb = ((size_t)(co * NB + b) * 4096 + row * 16 + n) * 1024 + (wv * 4 + q) * 64 + ln * 4;
    *(bf16x4*)&sout[sb] = sv;
  }
#pragma unroll
  for (int m = 1; m < 16; m <<= 1) {
    ssum += __shfl_xor(ssum, m, 64);
    ssq  += __shfl_xor(ssq, m, 64);
  }
  if ((lane & 15) == 0) {
    reds[wv * 4 + q] = ssum;
    reds[16 + wv * 4 + q] = ssq;
  }

  __syncthreads();
  if (t < 32) {
    float val;
    if (t < 16) {
      val = 0.f;
#pragma unroll
      for (int k = 0; k < 16; ++k) val += redp[k * 16 + t];
    } else {
      int kind = (t >> 3) & 1, g = t & 7;
      int wvv = g >> 1, qp = g & 1;
      val = reds[kind * 16 + wvv * 4 + qp * 2] + reds[kind * 16 + wvv * 4 + qp * 2 + 1];
    }
    const int bf1 = (co * 2 + b) * 256 + row;
    p1[(size_t)bf1 * 32 + t] = val;
  }
}

// ================ K2: per-block nrm1 reduce + norm1+relu staging + qc_conv1 + stats2 partials ================
__global__ __launch_bounds__(256) void K2(
    const __bf16* __restrict__ xt, const __bf16* __restrict__ A1,
    const float* __restrict__ p1, const float* __restrict__ g1, const float* __restrict__ be1,
    const float* __restrict__ bias1,
    __bf16* __restrict__ h, float* __restrict__ p2) {
  // XCD swizzle: band of 64 consecutive tiles per XCD for halo L2 locality
  const int blk = ((blockIdx.x & 7) << 6) | (blockIdx.x >> 3);
  const int tx = blk & 15, ty = blk >> 4;
  const int b = blockIdx.y;
  const int y0p = ty * 8, x0p = tx * 16;
  __shared__ __attribute__((aligned(16))) __bf16 tl[2][153 * 72];
  __shared__ double redn[16];
  __shared__ float sc[64], sh[64];
  __shared__ float lst[16];
  const int t = threadIdx.x;

  // prologue: reduce p1 stats1 (16 cols x 512 rows for our b) -> nrm1
  {
    const int col = t >> 4, sub = t & 15;    // 16 cols x 16 subs
    double v = 0.0;
    for (int j = sub; j < 512; j += 16) {
      int cc = j >> 8, rr = j & 255;
      v += (double)p1[((size_t)(cc * 2 + b) * 256 + rr) * 32 + col];
    }
    v += __shfl_xor(v, 1, 64);
    v += __shfl_xor(v, 2, 64);
    v += __shfl_xor(v, 4, 64);
    v += __shfl_xor(v, 8, 64);
    if (sub == 0) redn[col] = v;
  }
  if (t < 16) lst[t] = 0.f;
  __syncthreads();
  if (t < 64) {
    int g = t >> 3;
    double mean = redn[g] * INV_N;
    double var  = redn[8 + g] * INV_N - mean * mean;
    float inv = rsqrtf((float)var + EPSV);
    float s_ = inv * g1[t];
    sc[t] = s_;
    sh[t] = be1[t] - (float)mean * s_;
  }
  __syncthreads();

  // staging: fixed 10 predicated iterations
#pragma unroll
  for (int i = 0; i < 10; ++i) {
    int u = t + i * 256;
    if (u < 2 * 153 * 8) {
      int cs = u / 1224;
      int rr = u - cs * 1224;
      int px = rr >> 3, cg = rr & 7;
      int ly = px / 17, lx = px - ly * 17;
      int gy = y0p + ly - cs, gx = x0p + lx - cs;
      bf16x8 v;
#pragma unroll
      for (int j = 0; j < 8; ++j) v[j] = (__bf16)0.f;
      if ((unsigned)gy < 256u && (unsigned)gx < 256u) {
        bf16x8 raw = *(const bf16x8*)&xt[(((size_t)(cs * NB + b) * WD + gy) * WD + gx) * 64 + cg * 8];
#pragma unroll
        for (int j = 0; j < 8; ++j) {
          float f = fmaf((float)raw[j], sc[cg * 8 + j], sh[cg * 8 + j]);
          v[j] = (__bf16)fmaxf(f, 0.f);
        }
      }
      *(bf16x8*)&tl[cs][px * 72 + cg * 8] = v;
    }
  }
  __syncthreads();

  const int wv = t >> 6, lane = t & 63, ln = lane & 15, q = lane >> 4;
  const int co = wv & 1, mh = wv >> 1;
  const int q8 = q * 8;
  bf16x8 af[2][10];
#pragma unroll
  for (int m = 0; m < 2; ++m)
#pragma unroll
    for (int kk = 0; kk < 10; ++kk)
      af[m][kk] = *(const bf16x8*)&A1[(mh * 32 + m * 16 + ln) * 320 + kk * 32 + q8];

  f32x4 acc[8][2];
#pragma unroll
  for (int n = 0; n < 8; ++n)
#pragma unroll
    for (int m = 0; m < 2; ++m) acc[n][m] = (f32x4){0.f, 0.f, 0.f, 0.f};

  const __bf16* tc = tl[co];
  const __bf16* to = tl[1 - co];
#pragma unroll
  for (int n = 0; n < 8; ++n) {
    const int cpix = co ? ((n + 1) * 17 + ln + 1) : (n * 17 + ln);
    const int tb = n * 17 + ln;
    const __bf16* pc = tc + cpix * 72 + q8;
    const __bf16* p0 = to + tb * 72 + q8;
    const __bf16* p1p = to + (tb + 1) * 72 + q8;
    const __bf16* p2p = to + (tb + 17) * 72 + q8;
    const __bf16* p3 = to + (tb + 18) * 72 + q8;
    bf16x8 bb;
    bb = *(const bf16x8*)pc;         acc[n][0]=MFMA16(af[0][0],bb,acc[n][0]); acc[n][1]=MFMA16(af[1][0],bb,acc[n][1]);
    bb = *(const bf16x8*)(pc + 32);  acc[n][0]=MFMA16(af[0][1],bb,acc[n][0]); acc[n][1]=MFMA16(af[1][1],bb,acc[n][1]);
    bb = *(const bf16x8*)p0;         acc[n][0]=MFMA16(af[0][2],bb,acc[n][0]); acc[n][1]=MFMA16(af[1][2],bb,acc[n][1]);
    bb = *(const bf16x8*)(p0 + 32);  acc[n][0]=MFMA16(af[0][3],bb,acc[n][0]); acc[n][1]=MFMA16(af[1][3],bb,acc[n][1]);
    bb = *(const bf16x8*)p1p;        acc[n][0]=MFMA16(af[0][4],bb,acc[n][0]); acc[n][1]=MFMA16(af[1][4],bb,acc[n][1]);
    bb = *(const bf16x8*)(p1p + 32); acc[n][0]=MFMA16(af[0][5],bb,acc[n][0]); acc[n][1]=MFMA16(af[1][5],bb,acc[n][1]);
    bb = *(const bf16x8*)p2p;        acc[n][0]=MFMA16(af[0][6],bb,acc[n][0]); acc[n][1]=MFMA16(af[1][6],bb,acc[n][1]);
    bb = *(const bf16x8*)(p2p + 32); acc[n][0]=MFMA16(af[0][7],bb,acc[n][0]); acc[n][1]=MFMA16(af[1][7],bb,acc[n][1]);
    bb = *(const bf16x8*)p3;         acc[n][0]=MFMA16(af[0][8],bb,acc[n][0]); acc[n][1]=MFMA16(af[1][8],bb,acc[n][1]);
    bb = *(const bf16x8*)(p3 + 32);  acc[n][0]=MFMA16(af[0][9],bb,acc[n][0]); acc[n][1]=MFMA16(af[1][9],bb,acc[n][1]);
  }

  __syncthreads();   // all waves done reading tl — safe to overwrite with h values

  float s2s[2] = {0.f, 0.f}, s2q[2] = {0.f, 0.f};
  float bia[2][4];
#pragma unroll
  for (int m = 0; m < 2; ++m)
#pragma unroll
    for (int r = 0; r < 4; ++r) bia[m][r] = bias1[mh * 32 + m * 16 + q * 4 + r];

#pragma unroll
  for (int n = 0; n < 8; ++n)
#pragma unroll
    for (int m = 0; m < 2; ++m) {
      bf16x4 hv;
#pragma unroll
      for (int r = 0; r < 4; ++r) {
        float v = acc[n][m][r] + bia[m][r];
        s2s[m] += v;
        s2q[m] = fmaf(v, v, s2q[m]);
        hv[r] = (__bf16)v;
      }
      *(bf16x4*)&tl[co][(n * 16 + ln) * 72 + mh * 32 + m * 16 + q * 4] = hv;
    }

#pragma unroll
  for (int m = 0; m < 2; ++m) {
    float a_ = s2s[m], c_ = s2q[m];
#pragma unroll
    for (int mk = 1; mk < 32; mk <<= 1) {
      a_ += __shfl_xor(a_, mk, 64);
      c_ += __shfl_xor(c_, mk, 64);
    }
    if ((lane & 31) == 0) {
      int g = mh * 4 + m * 2 + (q >> 1);
      atomicAdd(&lst[g], a_);
      atomicAdd(&lst[8 + g], c_);
    }
  }
  __syncthreads();

  // coalesced h store (NHWC), 16 B/lane
#pragma unroll
  for (int i = 0; i < 8; ++i) {
    int co2 = i >> 2;
    int idx = (i & 3) * 256 + t;
    int px = idx >> 3, chunk = idx & 7;
    int gy = y0p + (px >> 4), gx = x0p + (px & 15);
    bf16x8 vv = *(const bf16x8*)&tl[co2][px * 72 + chunk * 8];
    *(bf16x8*)&h[(((size_t)(co2 * NB + b) * WD + gy) * WD + gx) * 64 + chunk * 8] = vv;
  }

  if (t < 16) p2[((size_t)b * 512 + blockIdx.x) * 16 + t] = lst[t];
}

// ================ K3: per-block nrm2+nrmS reduce + norm2+relu staging + qc_conv2 + skip + fp32 out ================
__global__ __launch_bounds__(256) void K3(
    const __bf16* __restrict__ hin, const __bf16* __restrict__ A2,
    const float* __restrict__ p2, const float* __restrict__ p1,
    const float* __restrict__ g2, const float* __restrict__ be2, const float* __restrict__ bias2,
    const float* __restrict__ gsk, const float* __restrict__ besk,
    const __bf16* __restrict__ sin_, float* __restrict__ out) {
  const int blk = ((blockIdx.x & 7) << 6) | (blockIdx.x >> 3);
  const int tx = blk & 15, ty = blk >> 4;
  const int b = blockIdx.y;
  const int y0p = ty * 8, x0p = tx * 16;
  __shared__ __attribute__((aligned(16))) __bf16 tl[2][153 * 72];
  __shared__ double redn[32];
  __shared__ float sc2[64], sh2[64], scS[64], shS[64];
  const int t = threadIdx.x;

  // prologue: reduce p2 (nrm2, cols 0-15) and p1 skip cols (nrmS, cols 16-31)
  {
    const int col = t >> 3, sub = t & 7;    // 32 cols x 8 subs
    double v = 0.0;
    if (col < 16) {
      for (int j = sub; j < 512; j += 8)
        v += (double)p2[((size_t)b * 512 + j) * 16 + col];
    } else {
      for (int j = sub; j < 512; j += 8) {
        int cc = j >> 8, rr = j & 255;
        v += (double)p1[((size_t)(cc * 2 + b) * 256 + rr) * 32 + col];
      }
    }
    v += __shfl_xor(v, 1, 64);
    v += __shfl_xor(v, 2, 64);
    v += __shfl_xor(v, 4, 64);
    if (sub == 0) redn[col] = v;
  }
  __syncthreads();
  if (t < 128) {
    int half = t >> 6, ch = t & 63, g = ch >> 3;
    if (half == 0) {
      double mean = redn[g] * INV_N;
      double var  = redn[8 + g] * INV_N - mean * mean;
      float inv = rsqrtf((float)var + EPSV);
      float s_ = inv * g2[ch];
      sc2[ch] = s_;
      sh2[ch] = be2[ch] - (float)mean * s_;
    } else {
      double mean = redn[16 + g] * INV_N;
      double var  = redn[24 + g] * INV_N - mean * mean;
      float inv = rsqrtf((float)var + EPSV);
      float s_ = inv * gsk[ch];
      scS[ch] = s_;
      shS[ch] = besk[ch] - (float)mean * s_;
    }
  }
  __syncthreads();

#pragma unroll
  for (int i = 0; i < 10; ++i) {
    int u = t + i * 256;
    if (u < 2 * 153 * 8) {
      int cs = u / 1224;
      int rr = u - cs * 1224;
      int px = rr >> 3, cg = rr & 7;
      int ly = px / 17, lx = px - ly * 17;
      int gy = y0p + ly - cs, gx = x0p + lx - cs;
      bf16x8 v;
#pragma unroll
      for (int j = 0; j < 8; ++j) v[j] = (__bf16)0.f;
      if ((unsigned)gy < 256u && (unsigned)gx < 256u) {
        bf16x8 raw = *(const bf16x8*)&hin[(((size_t)(cs * NB + b) * WD + gy) * WD + gx) * 64 + cg * 8];
#pragma unroll
        for (int j = 0; j < 8; ++j) {
          float f = fmaf((float)raw[j], sc2[cg * 8 + j], sh2[cg * 8 + j]);
          v[j] = (__bf16)fmaxf(f, 0.f);
        }
      }
      *(bf16x8*)&tl[cs][px * 72 + cg * 8] = v;
    }
  }
  __syncthreads();

  const int wv = t >> 6, lane = t & 63, ln = lane & 15, q = lane >> 4;
  const int co = wv & 1, mh = wv >> 1;
  const int q8 = q * 8;
  bf16x8 af[2][10];
#pragma unroll
  for (int m = 0; m < 2; ++m)
#pragma unroll
    for (int kk = 0; kk < 10; ++kk)
      af[m][kk] = *(const bf16x8*)&A2[(mh * 32 + m * 16 + ln) * 320 + kk * 32 + q8];

  f32x4 acc[8][2];
#pragma unroll
  for (int n = 0; n < 8; ++n)
#pragma unroll
    for (int m = 0; m < 2; ++m) acc[n][m] = (f32x4){0.f, 0.f, 0.f, 0.f};

  const __bf16* tc = tl[co];
  const __bf16* to = tl[1 - co];
#pragma unroll
  for (int n = 0; n < 8; ++n) {
    const int cpix = co ? ((n + 1) * 17 + ln + 1) : (n * 17 + ln);
    const int tb = n * 17 + ln;
    const __bf16* pc = tc + cpix * 72 + q8;
    const __bf16* p0 = to + tb * 72 + q8;
    const __bf16* p1p = to + (tb + 1) * 72 + q8;
    const __bf16* p2p = to + (tb + 17) * 72 + q8;
    const __bf16* p3 = to + (tb + 18) * 72 + q8;
    bf16x8 bb;
    bb = *(const bf16x8*)pc;         acc[n][0]=MFMA16(af[0][0],bb,acc[n][0]); acc[n][1]=MFMA16(af[1][0],bb,acc[n][1]);
    bb = *(const bf16x8*)(pc + 32);  acc[n][0]=MFMA16(af[0][1],bb,acc[n][0]); acc[n][1]=MFMA16(af[1][1],bb,acc[n][1]);
    bb = *(const bf16x8*)p0;         acc[n][0]=MFMA16(af[0][2],bb,acc[n][0]); acc[n][1]=MFMA16(af[1][2],bb,acc[n][1]);
    bb = *(const bf16x8*)(p0 + 32);  acc[n][0]=MFMA16(af[0][3],bb,acc[n][0]); acc[n][1]=MFMA16(af[1][3],bb,acc[n][1]);
    bb = *(const bf16x8*)p1p;        acc[n][0]=MFMA16(af[0][4],bb,acc[n][0]); acc[n][1]=MFMA16(af[1][4],bb,acc[n][1]);
    bb = *(const bf16x8*)(p1p + 32); acc[n][0]=MFMA16(af[0][5],bb,acc[n][0]); acc[n][1]=MFMA16(af[1][5],bb,acc[n][1]);
    bb = *(const bf16x8*)p2p;        acc[n][0]=MFMA16(af[0][6],bb,acc[n][0]); acc[n][1]=MFMA16(af[1][6],bb,acc[n][1]);
    bb = *(const bf16x8*)(p2p + 32); acc[n][0]=MFMA16(af[0][7],bb,acc[n][0]); acc[n][1]=MFMA16(af[1][7],bb,acc[n][1]);
    bb = *(const bf16x8*)p3;         acc[n][0]=MFMA16(af[0][8],bb,acc[n][0]); acc[n][1]=MFMA16(af[1][8],bb,acc[n][1]);
    bb = *(const bf16x8*)(p3 + 32);  acc[n][0]=MFMA16(af[0][9],bb,acc[n][0]); acc[n][1]=MFMA16(af[1][9],bb,acc[n][1]);
  }

  float bia[2][4], sA[2][4], sB[2][4];
#pragma unroll
  for (int m = 0; m < 2; ++m)
#pragma unroll
    for (int r = 0; r < 4; ++r) {
      int ch = mh * 32 + m * 16 + q * 4 + r;
      bia[m][r] = bias2[ch];
      sA[m][r] = scS[ch];
      sB[m][r] = shS[ch];
    }

#pragma unroll
  for (int n = 0; n < 8; ++n) {
    int gy = y0p + n;
#pragma unroll
    for (int m = 0; m < 2; ++m) {
      int ch0 = mh * 32 + m * 16 + q * 4;
      size_t sb = ((size_t)(co * NB + b) * 4096 + gy * 16 + tx) * 1024 + (mh * 8 + m * 4 + q) * 64 + ln * 4;
      bf16x4 sv = *(const bf16x4*)&sin_[sb];
      size_t ob = ((size_t)(co * NB + b) * 64 + ch0) * HW + (size_t)gy * WD + x0p + ln;
#pragma unroll
      for (int r = 0; r < 4; ++r) {
        float v = acc[n][m][r] + bia[m][r] + fmaf((float)sv[r], sA[m][r], sB[m][r]);
        out[ob + (size_t)r * HW] = v;
      }
    }
  }
}

extern "C" void kernel_launch(void* const* d_in, const int* in_sizes, int n_in,
                              void* d_out, int out_size, void* d_ws, size_t ws_size,
                              hipStream_t stream) {
  (void)in_sizes; (void)n_in; (void)out_size; (void)ws_size;
  const float* x0    = (const float*)d_in[0];
  const float* x1    = (const float*)d_in[1];
  const float* g1    = (const float*)d_in[2];
  const float* b1    = (const float*)d_in[3];
  const float* w1c   = (const float*)d_in[4];
  const float* w1k   = (const float*)d_in[5];
  const float* bias1 = (const float*)d_in[6];
  const float* g2    = (const float*)d_in[7];
  const float* b2    = (const float*)d_in[8];
  const float* w2c   = (const float*)d_in[9];
  const float* w2k   = (const float*)d_in[10];
  const float* bias2 = (const float*)d_in[11];
  const float* wsk   = (const float*)d_in[12];
  const float* bsk   = (const float*)d_in[13];
  const float* gsk   = (const float*)d_in[14];
  const float* besk  = (const float*)d_in[15];

  char* ws = (char*)d_ws;
  float*  p1 = (float*)(ws + OFF_P1);
  float*  p2 = (float*)(ws + OFF_P2);
  __bf16* A1 = (__bf16*)(ws + OFF_A1);
  __bf16* A2 = (__bf16*)(ws + OFF_A2);
  __bf16* xt = (__bf16*)(ws + OFF_XT);
  __bf16* s  = (__bf16*)(ws + OFF_S);
  __bf16* h  = (__bf16*)(ws + OFF_H);

  K1<<<dim3(1026), 256, 0, stream>>>(x0, x1, wsk, bsk, w1c, w1k, w2c, w2k, xt, s, A1, A2, p1);
  K2<<<dim3(512, 2), 256, 0, stream>>>(xt, A1, p1, g1, b1, bias1, h, p2);
  K3<<<dim3(512, 2), 256, 0, stream>>>(h, A2, p2, p1, g2, b2, bias2, gsk, besk, s, (float*)d_out);
}